// Round 2
// baseline (904.796 us; speedup 1.0000x reference)
//
#include <hip/hip_runtime.h>

#define NN 50000
#define NE 800000
#define DIM 128
#define NB 1024
#define CTXL 50
#define BN_EPS 1e-5f
#define STRIPS 3125  // NN/16

// ---------------- ws layout (float offsets) ----------------
static const size_t OFF_Z    = 0;          // z fp32 [NN][128]            25.6 MB
static const size_t OFF_AH   = 6400000;    // Ah bf16 [NN][128]           12.8 MB
static const size_t OFF_AL   = 9600000;    // Al bf16 [NN][128]           12.8 MB
static const size_t OFF_EDG  = 12800000;   // (col,norm) pairs [NE][2]     6.4 MB
static const size_t OFF_RS   = 14400000;   // row_start [NN+1] int
static const size_t OFF_CUR  = 14450048;   // cursor [NN] int
static const size_t OFF_CNT  = 14500096;   // counts [NN] int
static const size_t OFF_STAT = 14550144;   // stats [256] f
static const size_t OFF_SCSH = 14550400;   // scale/shift [256] f
static const size_t OFF_WH   = 14550656;   // Wh bf16 [2][128][128]
static const size_t OFF_WL   = 14567040;   // Wl bf16 [2][128][128]

typedef __attribute__((ext_vector_type(8))) short s16x8;
typedef __attribute__((ext_vector_type(4))) float fx4;

__device__ __forceinline__ unsigned short f2bf(float f) {
    unsigned u = __float_as_uint(f);
    unsigned r = u + 0x7FFFu + ((u >> 16) & 1u);
    return (unsigned short)(r >> 16);
}
__device__ __forceinline__ float bf2f(unsigned short b) {
    return __uint_as_float((unsigned)b << 16);
}

// ---------------- CSR build ----------------
__global__ void hist_kernel(const int* __restrict__ row, int* __restrict__ counts) {
    int e = blockIdx.x * 256 + threadIdx.x;
    if (e < NE) atomicAdd(&counts[row[e]], 1);
}

__global__ __launch_bounds__(1024) void scan_kernel(const int* __restrict__ counts,
                                                    int* __restrict__ row_start,
                                                    int* __restrict__ cursor) {
    __shared__ int lds[1024];
    const int CHUNK = 49;  // 1024*49 = 50176 >= 50000
    int t = threadIdx.x;
    int base = t * CHUNK;
    int s = 0;
    for (int i = 0; i < CHUNK; i++) {
        int idx = base + i;
        if (idx < NN) s += counts[idx];
    }
    lds[t] = s;
    __syncthreads();
    for (int off = 1; off < 1024; off <<= 1) {
        int v = lds[t];
        int add = (t >= off) ? lds[t - off] : 0;
        __syncthreads();
        lds[t] = v + add;
        __syncthreads();
    }
    int run = (t == 0) ? 0 : lds[t - 1];
    for (int i = 0; i < CHUNK; i++) {
        int idx = base + i;
        if (idx < NN) {
            row_start[idx] = run;
            cursor[idx] = run;
            run += counts[idx];
        }
    }
    if (t == 1023) row_start[NN] = lds[1023];
}

__global__ void scatter_kernel(const int* __restrict__ row, const int* __restrict__ col,
                               const float* __restrict__ norm, int* __restrict__ cursor,
                               float* __restrict__ edge_s) {
    int e = blockIdx.x * 256 + threadIdx.x;
    if (e < NE) {
        int r = row[e];
        int p = atomicAdd(&cursor[r], 1);
        ((int*)edge_s)[2 * p] = col[e];
        edge_s[2 * p + 1] = norm[e];
    }
}

// ---------------- W split prep ----------------
__global__ void wsplit_kernel(const float* __restrict__ W, unsigned short* __restrict__ Wh,
                              unsigned short* __restrict__ Wl) {
    int i = blockIdx.x * 256 + threadIdx.x;
    if (i < 2 * DIM * DIM) {
        float v = W[i];
        unsigned short h = f2bf(v);
        Wh[i] = h;
        Wl[i] = f2bf(v - bf2f(h));
    }
}

// ---------------- aggregation: one wave per row, 4-edge pipelined, split-bf16 out ----------------
__global__ __launch_bounds__(256) void agg_split_kernel(const float* __restrict__ h,
                                                        const int* __restrict__ row_start,
                                                        const float* __restrict__ edge_s,
                                                        unsigned short* __restrict__ Ah,
                                                        unsigned short* __restrict__ Al) {
    int gw = (blockIdx.x * 256 + threadIdx.x) >> 6;
    int lane = threadIdx.x & 63;
    if (gw >= NN) return;
    int s = row_start[gw];
    int e = row_start[gw + 1];
    const int2* ep = (const int2*)edge_s;
    float ax = 0.f, ay = 0.f;
    int j = s;
    for (; j + 4 <= e; j += 4) {
        int2 p0 = ep[j], p1 = ep[j + 1], p2 = ep[j + 2], p3 = ep[j + 3];
        float2 v0 = *(const float2*)(h + (size_t)p0.x * DIM + lane * 2);
        float2 v1 = *(const float2*)(h + (size_t)p1.x * DIM + lane * 2);
        float2 v2 = *(const float2*)(h + (size_t)p2.x * DIM + lane * 2);
        float2 v3 = *(const float2*)(h + (size_t)p3.x * DIM + lane * 2);
        float w0 = __int_as_float(p0.y), w1 = __int_as_float(p1.y);
        float w2 = __int_as_float(p2.y), w3 = __int_as_float(p3.y);
        ax = fmaf(w0, v0.x, ax); ay = fmaf(w0, v0.y, ay);
        ax = fmaf(w1, v1.x, ax); ay = fmaf(w1, v1.y, ay);
        ax = fmaf(w2, v2.x, ax); ay = fmaf(w2, v2.y, ay);
        ax = fmaf(w3, v3.x, ax); ay = fmaf(w3, v3.y, ay);
    }
    for (; j < e; j++) {
        int2 p = ep[j];
        float2 v = *(const float2*)(h + (size_t)p.x * DIM + lane * 2);
        float w = __int_as_float(p.y);
        ax = fmaf(w, v.x, ax); ay = fmaf(w, v.y, ay);
    }
    size_t o = (size_t)gw * DIM + lane * 2;
    unsigned short hx = f2bf(ax), hy = f2bf(ay);
    *(ushort2*)(Ah + o) = make_ushort2(hx, hy);
    *(ushort2*)(Al + o) = make_ushort2(f2bf(ax - bf2f(hx)), f2bf(ay - bf2f(hy)));
}

// ---------------- z = relu(agg @ W^T) via split-bf16 MFMA, fused BN partial sums ----------------
// W held register-resident per wave (blockIdx.y selects channel half).
// mfma_f32_16x16x32_bf16: A-op lane l holds A[l&15][(l>>4)*8+j]; B-op lane l holds B[(l>>4)*8+j][l&15];
// D: col=lane&15, row=(lane>>4)*4+reg. A-op = W rows (channels), B-op = agg rows.
__global__ __launch_bounds__(256) void gemm_mfma_kernel(const unsigned short* __restrict__ Ah,
                                                        const unsigned short* __restrict__ Al,
                                                        const unsigned short* __restrict__ Wh,
                                                        const unsigned short* __restrict__ Wl,
                                                        float* __restrict__ z,
                                                        float* __restrict__ stats) {
    int lane = threadIdx.x & 63;
    int r16 = lane & 15;
    int kg = lane >> 4;
    int chalf = blockIdx.y;
    int wv = (blockIdx.x * 256 + threadIdx.x) >> 6;
    int nw = gridDim.x * 4;

    s16x8 wf[4][4][2];  // [ctile][kstep][hi/lo]
    #pragma unroll
    for (int ct = 0; ct < 4; ct++) {
        #pragma unroll
        for (int ks = 0; ks < 4; ks++) {
            size_t off = (size_t)(chalf * 64 + ct * 16 + r16) * DIM + ks * 32 + kg * 8;
            wf[ct][ks][0] = *(const s16x8*)(Wh + off);
            wf[ct][ks][1] = *(const s16x8*)(Wl + off);
        }
    }

    float bsum[4][4] = {{0.f}}, bsq[4][4] = {{0.f}};

    for (int strip = wv; strip < STRIPS; strip += nw) {
        size_t abase = (size_t)(strip * 16 + r16) * DIM + kg * 8;
        fx4 acc[4];
        #pragma unroll
        for (int ct = 0; ct < 4; ct++) acc[ct] = (fx4){0.f, 0.f, 0.f, 0.f};
        #pragma unroll
        for (int ks = 0; ks < 4; ks++) {
            s16x8 bh = *(const s16x8*)(Ah + abase + ks * 32);
            s16x8 bl = *(const s16x8*)(Al + abase + ks * 32);
            #pragma unroll
            for (int ct = 0; ct < 4; ct++) {
                acc[ct] = __builtin_amdgcn_mfma_f32_16x16x32_bf16(wf[ct][ks][0], bh, acc[ct], 0, 0, 0);
                acc[ct] = __builtin_amdgcn_mfma_f32_16x16x32_bf16(wf[ct][ks][1], bh, acc[ct], 0, 0, 0);
                acc[ct] = __builtin_amdgcn_mfma_f32_16x16x32_bf16(wf[ct][ks][0], bl, acc[ct], 0, 0, 0);
            }
        }
        size_t zrow = (size_t)(strip * 16 + r16) * DIM + chalf * 64 + kg * 4;
        #pragma unroll
        for (int ct = 0; ct < 4; ct++) {
            float4 o;
            o.x = fmaxf(acc[ct][0], 0.f);
            o.y = fmaxf(acc[ct][1], 0.f);
            o.z = fmaxf(acc[ct][2], 0.f);
            o.w = fmaxf(acc[ct][3], 0.f);
            bsum[ct][0] += o.x; bsq[ct][0] += o.x * o.x;
            bsum[ct][1] += o.y; bsq[ct][1] += o.y * o.y;
            bsum[ct][2] += o.z; bsq[ct][2] += o.z * o.z;
            bsum[ct][3] += o.w; bsq[ct][3] += o.w * o.w;
            *(float4*)(z + zrow + ct * 16) = o;
        }
    }

    // channel c is shared by the 16 lanes with the same kg (r16 = 0..15): butterfly over lane bits 0-3
    #pragma unroll
    for (int ct = 0; ct < 4; ct++) {
        #pragma unroll
        for (int jj = 0; jj < 4; jj++) {
            float s = bsum[ct][jj], q = bsq[ct][jj];
            #pragma unroll
            for (int off = 1; off <= 8; off <<= 1) {
                s += __shfl_xor(s, off);
                q += __shfl_xor(q, off);
            }
            if (r16 == 0) {
                int c = chalf * 64 + ct * 16 + kg * 4 + jj;
                unsafeAtomicAdd(&stats[c], s);
                unsafeAtomicAdd(&stats[128 + c], q);
            }
        }
    }
}

__global__ void bn_finalize_kernel(float* __restrict__ stats, const float* __restrict__ gamma,
                                   const float* __restrict__ beta, float* __restrict__ scsh) {
    int c = threadIdx.x;
    if (c < 128) {
        float mu = stats[c] * (1.f / (float)NN);
        float ex2 = stats[128 + c] * (1.f / (float)NN);
        float var = ex2 - mu * mu;
        float sc = gamma[c] / sqrtf(var + BN_EPS);
        scsh[c] = sc;
        scsh[128 + c] = beta[c] - mu * sc;
        stats[c] = 0.f;  // reset for next layer
        stats[128 + c] = 0.f;
    }
}

// ---------------- h_out = h_in + z*scale + shift ----------------
__global__ __launch_bounds__(256) void residual_kernel(const float* hin,
                                                       const float* z,
                                                       const float* __restrict__ scsh,
                                                       float* hout) {
    int i = blockIdx.x * 256 + threadIdx.x;  // float4 index
    if (i >= NN * DIM / 4) return;
    int c = (i * 4) & 127;
    float4 zv = reinterpret_cast<const float4*>(z)[i];
    float4 hv = reinterpret_cast<const float4*>(hin)[i];
    float4 sc = *reinterpret_cast<const float4*>(scsh + c);
    float4 sh = *reinterpret_cast<const float4*>(scsh + 128 + c);
    float4 o;
    o.x = hv.x + zv.x * sc.x + sh.x;
    o.y = hv.y + zv.y * sc.y + sh.y;
    o.z = hv.z + zv.z * sc.z + sh.z;
    o.w = hv.w + zv.w * sc.w + sh.w;
    reinterpret_cast<float4*>(hout)[i] = o;
}

// ---------------- fused batch head ----------------
__global__ __launch_bounds__(256) void batch_kernel(const int* __restrict__ ctx_ids,
                                                    const int* __restrict__ miss_ids,
                                                    const int* __restrict__ vocab_to_fg,
                                                    const float* __restrict__ emb_table,
                                                    const float* __restrict__ graph,
                                                    const float* __restrict__ attn_w,
                                                    const float* __restrict__ attn_b,
                                                    const float* __restrict__ fusion_w,
                                                    const float* __restrict__ fusion_b,
                                                    const float* __restrict__ proj1_w,
                                                    const float* __restrict__ proj1_b,
                                                    const float* __restrict__ proj2_w,
                                                    const float* __restrict__ proj2_b,
                                                    float* __restrict__ query) {
    int b = blockIdx.x;
    int tid = threadIdx.x;
    __shared__ float ctx[CTXL][129];
    __shared__ float aw[128];
    __shared__ float lg[64];
    __shared__ __align__(16) float qin[256];
    __shared__ __align__(16) float cat[256];
    __shared__ __align__(16) float q1[256];

    if (tid < 128) aw[tid] = attn_w[tid];
    for (int f = tid; f < CTXL * 128; f += 256) {
        int t = f >> 7, d = f & 127;
        int vid = ctx_ids[b * CTXL + t];
        ctx[t][d] = emb_table[(size_t)vid * DIM + d];
    }
    __syncthreads();

    if (tid < CTXL) {
        float s = 0.f;
        for (int k = 0; k < 128; k++) s += ctx[tid][k] * aw[k];
        lg[tid] = s + attn_b[0];
    }
    __syncthreads();

    if (tid < 64) {
        float v = (tid < CTXL) ? lg[tid] : -INFINITY;
        float m = v;
        for (int off = 32; off; off >>= 1) m = fmaxf(m, __shfl_xor(m, off));
        float e = (tid < CTXL) ? expf(v - m) : 0.f;
        float s = e;
        for (int off = 32; off; off >>= 1) s += __shfl_xor(s, off);
        if (tid < CTXL) lg[tid] = e / s;
    }
    __syncthreads();

    if (tid < 128) {
        float s = 0.f;
        for (int t = 0; t < CTXL; t++) s += lg[t] * ctx[t][tid];
        qin[tid] = s;
    }
    int mid = miss_ids[b];
    if (tid < 128) {
        cat[tid] = emb_table[(size_t)mid * DIM + tid];
    } else {
        int d = tid - 128;
        int fg = vocab_to_fg[mid];
        cat[tid] = (fg >= 0) ? graph[(size_t)fg * DIM + d] : 0.f;
    }
    __syncthreads();

    if (tid < 128) {
        float s = fusion_b[tid];
        const float4* wr = reinterpret_cast<const float4*>(fusion_w + (size_t)tid * 256);
        const float4* cr = reinterpret_cast<const float4*>(cat);
        for (int k = 0; k < 64; k++) {
            float4 w4 = wr[k];
            float4 c4 = cr[k];
            s += w4.x * c4.x + w4.y * c4.y + w4.z * c4.z + w4.w * c4.w;
        }
        qin[128 + tid] = s;
    }
    __syncthreads();

    {
        float s = proj1_b[tid];
        const float4* wr = reinterpret_cast<const float4*>(proj1_w + (size_t)tid * 256);
        const float4* cr = reinterpret_cast<const float4*>(qin);
        for (int k = 0; k < 64; k++) {
            float4 w4 = wr[k];
            float4 c4 = cr[k];
            s += w4.x * c4.x + w4.y * c4.y + w4.z * c4.z + w4.w * c4.w;
        }
        q1[tid] = fmaxf(s, 0.f);
    }
    __syncthreads();

    if (tid < 128) {
        float s = proj2_b[tid];
        const float4* wr = reinterpret_cast<const float4*>(proj2_w + (size_t)tid * 256);
        const float4* cr = reinterpret_cast<const float4*>(q1);
        for (int k = 0; k < 64; k++) {
            float4 w4 = wr[k];
            float4 c4 = cr[k];
            s += w4.x * c4.x + w4.y * c4.y + w4.z * c4.z + w4.w * c4.w;
        }
        query[(size_t)b * DIM + tid] = s;
    }
}

extern "C" void kernel_launch(void* const* d_in, const int* in_sizes, int n_in,
                              void* d_out, int out_size, void* d_ws, size_t ws_size,
                              hipStream_t stream) {
    const int*   edge_index = (const int*)d_in[0];
    const float* norm       = (const float*)d_in[1];
    const int*   ctx_ids    = (const int*)d_in[2];
    const int*   miss_ids   = (const int*)d_in[3];
    const int*   vocab_to_fg= (const int*)d_in[4];
    const float* emb_table  = (const float*)d_in[5];
    const float* fg_emb     = (const float*)d_in[6];
    const float* gc_w       = (const float*)d_in[7];
    const float* bn_gamma   = (const float*)d_in[8];
    const float* bn_beta    = (const float*)d_in[9];
    const float* attn_w     = (const float*)d_in[10];
    const float* attn_b     = (const float*)d_in[11];
    const float* fusion_w   = (const float*)d_in[12];
    const float* fusion_b   = (const float*)d_in[13];
    const float* proj1_w    = (const float*)d_in[14];
    const float* proj1_b    = (const float*)d_in[15];
    const float* proj2_w    = (const float*)d_in[16];
    const float* proj2_b    = (const float*)d_in[17];

    const int* row = edge_index;
    const int* col = edge_index + NE;

    float* ws = (float*)d_ws;
    float*          z      = ws + OFF_Z;
    unsigned short* Ah     = (unsigned short*)(ws + OFF_AH);
    unsigned short* Al     = (unsigned short*)(ws + OFF_AL);
    float*          edge_s = ws + OFF_EDG;
    int*   row_start = (int*)(ws + OFF_RS);
    int*   cursor    = (int*)(ws + OFF_CUR);
    int*   counts    = (int*)(ws + OFF_CNT);
    float* stats     = ws + OFF_STAT;
    float* scsh      = ws + OFF_SCSH;
    unsigned short* Wh = (unsigned short*)(ws + OFF_WH);
    unsigned short* Wl = (unsigned short*)(ws + OFF_WL);

    float* query = (float*)d_out;
    float* G     = (float*)d_out + (size_t)NB * DIM;  // graph_embs, doubles as h

    hipMemsetAsync(counts, 0, NN * sizeof(int), stream);
    hipMemsetAsync(stats, 0, 256 * sizeof(float), stream);

    const int EB = (NE + 255) / 256;  // 3125
    wsplit_kernel<<<128, 256, 0, stream>>>(gc_w, Wh, Wl);
    hist_kernel<<<EB, 256, 0, stream>>>(row, counts);
    scan_kernel<<<1, 1024, 0, stream>>>(counts, row_start, cursor);
    scatter_kernel<<<EB, 256, 0, stream>>>(row, col, norm, cursor, edge_s);

    const int AGG_B = NN / 4;                 // 12500 blocks, one wave per row
    const int RES_B = (NN * DIM / 4) / 256;   // 6250
    dim3 gemm_grid(392, 2);

    // ---- layer 1 ----
    agg_split_kernel<<<AGG_B, 256, 0, stream>>>(fg_emb, row_start, edge_s, Ah, Al);
    gemm_mfma_kernel<<<gemm_grid, 256, 0, stream>>>(Ah, Al, Wh, Wl, z, stats);
    bn_finalize_kernel<<<1, 128, 0, stream>>>(stats, bn_gamma, bn_beta, scsh);
    residual_kernel<<<RES_B, 256, 0, stream>>>(fg_emb, z, scsh, G);

    // ---- layer 2 ----
    agg_split_kernel<<<AGG_B, 256, 0, stream>>>(G, row_start, edge_s, Ah, Al);
    gemm_mfma_kernel<<<gemm_grid, 256, 0, stream>>>(Ah, Al, Wh + DIM * DIM, Wl + DIM * DIM, z, stats);
    bn_finalize_kernel<<<1, 128, 0, stream>>>(stats, bn_gamma + 128, bn_beta + 128, scsh);
    residual_kernel<<<RES_B, 256, 0, stream>>>(G, z, scsh, G);

    // ---- batch head ----
    batch_kernel<<<NB, 256, 0, stream>>>(ctx_ids, miss_ids, vocab_to_fg, emb_table, G,
                                         attn_w, attn_b, fusion_w, fusion_b,
                                         proj1_w, proj1_b, proj2_w, proj2_b, query);
}

// Round 3
// 628.015 us; speedup vs baseline: 1.4407x; 1.4407x over previous
//
#include <hip/hip_runtime.h>

#define NN 50000
#define NE 800000
#define DIM 128
#define NB 1024
#define CTXL 50
#define BN_EPS 1e-5f
#define STRIPS 3125  // NN/16

// ---------------- ws layout (float offsets) ----------------
static const size_t OFF_Z    = 0;          // z fp32 [NN][128]          25.6 MB
static const size_t OFF_AH   = 6400000;    // Ah bf16 [NN][128]         12.8 MB
static const size_t OFF_HBF  = 9600000;    // hbf bf16 [NN][128]        12.8 MB (fgbf then Gbf)
static const size_t OFF_EDG  = 12800000;   // (col,norm) pairs [NE][2]   6.4 MB
static const size_t OFF_RS   = 14400000;   // row_start [NN+1] int
static const size_t OFF_CUR  = 14450048;   // cursor [NN] int
static const size_t OFF_CNT  = 14500096;   // counts [NN] int
static const size_t OFF_STAT = 14550144;   // stats [256] f
static const size_t OFF_SCSH = 14550400;   // scale/shift [256] f
static const size_t OFF_WH   = 14550656;   // Wh bf16 [2][128][128]
static const size_t OFF_WL   = 14567040;   // Wl bf16 [2][128][128]

typedef __attribute__((ext_vector_type(8))) short s16x8;
typedef __attribute__((ext_vector_type(4))) float fx4;

__device__ __forceinline__ unsigned short f2bf(float f) {
    unsigned u = __float_as_uint(f);
    unsigned r = u + 0x7FFFu + ((u >> 16) & 1u);
    return (unsigned short)(r >> 16);
}
__device__ __forceinline__ float bf2f(unsigned short b) {
    return __uint_as_float((unsigned)b << 16);
}

// ---------------- CSR build ----------------
__global__ void hist_kernel(const int* __restrict__ row, int* __restrict__ counts) {
    int e = blockIdx.x * 256 + threadIdx.x;
    if (e < NE) atomicAdd(&counts[row[e]], 1);
}

__global__ __launch_bounds__(1024) void scan_kernel(const int* __restrict__ counts,
                                                    int* __restrict__ row_start,
                                                    int* __restrict__ cursor) {
    __shared__ int lds[1024];
    const int CHUNK = 49;  // 1024*49 = 50176 >= 50000
    int t = threadIdx.x;
    int base = t * CHUNK;
    int s = 0;
    for (int i = 0; i < CHUNK; i++) {
        int idx = base + i;
        if (idx < NN) s += counts[idx];
    }
    lds[t] = s;
    __syncthreads();
    for (int off = 1; off < 1024; off <<= 1) {
        int v = lds[t];
        int add = (t >= off) ? lds[t - off] : 0;
        __syncthreads();
        lds[t] = v + add;
        __syncthreads();
    }
    int run = (t == 0) ? 0 : lds[t - 1];
    for (int i = 0; i < CHUNK; i++) {
        int idx = base + i;
        if (idx < NN) {
            row_start[idx] = run;
            cursor[idx] = run;
            run += counts[idx];
        }
    }
    if (t == 1023) row_start[NN] = lds[1023];
}

__global__ void scatter_kernel(const int* __restrict__ row, const int* __restrict__ col,
                               const float* __restrict__ norm, int* __restrict__ cursor,
                               float* __restrict__ edge_s) {
    int e = blockIdx.x * 256 + threadIdx.x;
    if (e < NE) {
        int r = row[e];
        int p = atomicAdd(&cursor[r], 1);
        ((int*)edge_s)[2 * p] = col[e];
        edge_s[2 * p + 1] = norm[e];
    }
}

// ---------------- prep: W split, h cast ----------------
__global__ void wsplit_kernel(const float* __restrict__ W, unsigned short* __restrict__ Wh,
                              unsigned short* __restrict__ Wl) {
    int i = blockIdx.x * 256 + threadIdx.x;
    if (i < 2 * DIM * DIM) {
        float v = W[i];
        unsigned short h = f2bf(v);
        Wh[i] = h;
        Wl[i] = f2bf(v - bf2f(h));
    }
}

__global__ void cast_bf_kernel(const float* __restrict__ in, unsigned short* __restrict__ out) {
    int i = blockIdx.x * 256 + threadIdx.x;  // float4 index
    if (i >= NN * DIM / 4) return;
    float4 v = reinterpret_cast<const float4*>(in)[i];
    ushort4 o = make_ushort4(f2bf(v.x), f2bf(v.y), f2bf(v.z), f2bf(v.w));
    reinterpret_cast<ushort4*>(out)[i] = o;
}

// ---------------- aggregation: one wave per row, gather bf16 rows, fp32 accum ----------------
__global__ __launch_bounds__(256) void agg_bf_kernel(const unsigned short* __restrict__ hbf,
                                                     const int* __restrict__ row_start,
                                                     const float* __restrict__ edge_s,
                                                     unsigned short* __restrict__ Ah) {
    int gw = (blockIdx.x * 256 + threadIdx.x) >> 6;
    int lane = threadIdx.x & 63;
    if (gw >= NN) return;
    int s = row_start[gw];
    int e = row_start[gw + 1];
    const int2* ep = (const int2*)edge_s;
    float ax = 0.f, ay = 0.f;
    int j = s;
    for (; j + 4 <= e; j += 4) {
        int2 p0 = ep[j], p1 = ep[j + 1], p2 = ep[j + 2], p3 = ep[j + 3];
        ushort2 v0 = *(const ushort2*)(hbf + (size_t)p0.x * DIM + lane * 2);
        ushort2 v1 = *(const ushort2*)(hbf + (size_t)p1.x * DIM + lane * 2);
        ushort2 v2 = *(const ushort2*)(hbf + (size_t)p2.x * DIM + lane * 2);
        ushort2 v3 = *(const ushort2*)(hbf + (size_t)p3.x * DIM + lane * 2);
        float w0 = __int_as_float(p0.y), w1 = __int_as_float(p1.y);
        float w2 = __int_as_float(p2.y), w3 = __int_as_float(p3.y);
        ax = fmaf(w0, bf2f(v0.x), ax); ay = fmaf(w0, bf2f(v0.y), ay);
        ax = fmaf(w1, bf2f(v1.x), ax); ay = fmaf(w1, bf2f(v1.y), ay);
        ax = fmaf(w2, bf2f(v2.x), ax); ay = fmaf(w2, bf2f(v2.y), ay);
        ax = fmaf(w3, bf2f(v3.x), ax); ay = fmaf(w3, bf2f(v3.y), ay);
    }
    for (; j < e; j++) {
        int2 p = ep[j];
        ushort2 v = *(const ushort2*)(hbf + (size_t)p.x * DIM + lane * 2);
        float w = __int_as_float(p.y);
        ax = fmaf(w, bf2f(v.x), ax); ay = fmaf(w, bf2f(v.y), ay);
    }
    *(ushort2*)(Ah + (size_t)gw * DIM + lane * 2) = make_ushort2(f2bf(ax), f2bf(ay));
}

// ---------------- z = relu(agg @ W^T) via MFMA, W register-resident (32 channels/wave) ----------------
// mfma_f32_16x16x32_bf16: A-op lane l holds A[l&15][(l>>4)*8+j]; B-op lane l holds B[(l>>4)*8+j][l&15];
// D: col(lane&15)=B-row(node), row((lane>>4)*4+reg)=A-row(channel).
__global__ __launch_bounds__(256) void gemm_mfma_kernel(const unsigned short* __restrict__ Ah,
                                                        const unsigned short* __restrict__ Wh,
                                                        const unsigned short* __restrict__ Wl,
                                                        float* __restrict__ z,
                                                        float* __restrict__ stats) {
    int lane = threadIdx.x & 63;
    int r16 = lane & 15;
    int kg = lane >> 4;
    int cq = blockIdx.y;                       // 32-channel group, 0..3
    int wv = (blockIdx.x * 256 + threadIdx.x) >> 6;
    int nw = gridDim.x * 4;

    s16x8 wf[2][4][2];  // [ctile][kstep][hi/lo] = 64 VGPRs
    #pragma unroll
    for (int ct = 0; ct < 2; ct++) {
        #pragma unroll
        for (int ks = 0; ks < 4; ks++) {
            size_t off = (size_t)(cq * 32 + ct * 16 + r16) * DIM + ks * 32 + kg * 8;
            wf[ct][ks][0] = *(const s16x8*)(Wh + off);
            wf[ct][ks][1] = *(const s16x8*)(Wl + off);
        }
    }

    float bsum[2][4] = {{0.f}}, bsq[2][4] = {{0.f}};

    for (int strip = wv; strip < STRIPS; strip += nw) {
        size_t abase = (size_t)(strip * 16 + r16) * DIM + kg * 8;
        fx4 acc[2];
        acc[0] = (fx4){0.f, 0.f, 0.f, 0.f};
        acc[1] = (fx4){0.f, 0.f, 0.f, 0.f};
        #pragma unroll
        for (int ks = 0; ks < 4; ks++) {
            s16x8 b = *(const s16x8*)(Ah + abase + ks * 32);
            #pragma unroll
            for (int ct = 0; ct < 2; ct++) {
                acc[ct] = __builtin_amdgcn_mfma_f32_16x16x32_bf16(wf[ct][ks][0], b, acc[ct], 0, 0, 0);
                acc[ct] = __builtin_amdgcn_mfma_f32_16x16x32_bf16(wf[ct][ks][1], b, acc[ct], 0, 0, 0);
            }
        }
        size_t zrow = (size_t)(strip * 16 + r16) * DIM + cq * 32 + kg * 4;
        #pragma unroll
        for (int ct = 0; ct < 2; ct++) {
            float4 o;
            o.x = fmaxf(acc[ct][0], 0.f);
            o.y = fmaxf(acc[ct][1], 0.f);
            o.z = fmaxf(acc[ct][2], 0.f);
            o.w = fmaxf(acc[ct][3], 0.f);
            bsum[ct][0] += o.x; bsq[ct][0] += o.x * o.x;
            bsum[ct][1] += o.y; bsq[ct][1] += o.y * o.y;
            bsum[ct][2] += o.z; bsq[ct][2] += o.z * o.z;
            bsum[ct][3] += o.w; bsq[ct][3] += o.w * o.w;
            *(float4*)(z + zrow + ct * 16) = o;
        }
    }

    // channel = cq*32 + ct*16 + kg*4 + jj, shared by the 16 lanes differing in r16 (lane bits 0-3)
    #pragma unroll
    for (int ct = 0; ct < 2; ct++) {
        #pragma unroll
        for (int jj = 0; jj < 4; jj++) {
            float s = bsum[ct][jj], q = bsq[ct][jj];
            #pragma unroll
            for (int off = 1; off <= 8; off <<= 1) {
                s += __shfl_xor(s, off);
                q += __shfl_xor(q, off);
            }
            if (r16 == 0) {
                int c = cq * 32 + ct * 16 + kg * 4 + jj;
                unsafeAtomicAdd(&stats[c], s);
                unsafeAtomicAdd(&stats[128 + c], q);
            }
        }
    }
}

__global__ void bn_finalize_kernel(float* __restrict__ stats, const float* __restrict__ gamma,
                                   const float* __restrict__ beta, float* __restrict__ scsh) {
    int c = threadIdx.x;
    if (c < 128) {
        float mu = stats[c] * (1.f / (float)NN);
        float ex2 = stats[128 + c] * (1.f / (float)NN);
        float var = ex2 - mu * mu;
        float sc = gamma[c] / sqrtf(var + BN_EPS);
        scsh[c] = sc;
        scsh[128 + c] = beta[c] - mu * sc;
        stats[c] = 0.f;  // reset for next layer
        stats[128 + c] = 0.f;
    }
}

// ---------------- h_out = h_in + z*scale + shift (+ optional bf16 emit) ----------------
__global__ __launch_bounds__(256) void residual_kernel(const float* hin,
                                                       const float* z,
                                                       const float* __restrict__ scsh,
                                                       float* hout,
                                                       unsigned short* hbf_out) {
    int i = blockIdx.x * 256 + threadIdx.x;  // float4 index
    if (i >= NN * DIM / 4) return;
    int c = (i * 4) & 127;
    float4 zv = reinterpret_cast<const float4*>(z)[i];
    float4 hv = reinterpret_cast<const float4*>(hin)[i];
    float4 sc = *reinterpret_cast<const float4*>(scsh + c);
    float4 sh = *reinterpret_cast<const float4*>(scsh + 128 + c);
    float4 o;
    o.x = hv.x + zv.x * sc.x + sh.x;
    o.y = hv.y + zv.y * sc.y + sh.y;
    o.z = hv.z + zv.z * sc.z + sh.z;
    o.w = hv.w + zv.w * sc.w + sh.w;
    reinterpret_cast<float4*>(hout)[i] = o;
    if (hbf_out) {
        ushort4 ob = make_ushort4(f2bf(o.x), f2bf(o.y), f2bf(o.z), f2bf(o.w));
        reinterpret_cast<ushort4*>(hbf_out)[i] = ob;
    }
}

// ---------------- fused batch head ----------------
__global__ __launch_bounds__(256) void batch_kernel(const int* __restrict__ ctx_ids,
                                                    const int* __restrict__ miss_ids,
                                                    const int* __restrict__ vocab_to_fg,
                                                    const float* __restrict__ emb_table,
                                                    const float* __restrict__ graph,
                                                    const float* __restrict__ attn_w,
                                                    const float* __restrict__ attn_b,
                                                    const float* __restrict__ fusion_w,
                                                    const float* __restrict__ fusion_b,
                                                    const float* __restrict__ proj1_w,
                                                    const float* __restrict__ proj1_b,
                                                    const float* __restrict__ proj2_w,
                                                    const float* __restrict__ proj2_b,
                                                    float* __restrict__ query) {
    int b = blockIdx.x;
    int tid = threadIdx.x;
    __shared__ float ctx[CTXL][129];
    __shared__ float aw[128];
    __shared__ float lg[64];
    __shared__ __align__(16) float qin[256];
    __shared__ __align__(16) float cat[256];
    __shared__ __align__(16) float q1[256];

    if (tid < 128) aw[tid] = attn_w[tid];
    for (int f = tid; f < CTXL * 128; f += 256) {
        int t = f >> 7, d = f & 127;
        int vid = ctx_ids[b * CTXL + t];
        ctx[t][d] = emb_table[(size_t)vid * DIM + d];
    }
    __syncthreads();

    if (tid < CTXL) {
        float s = 0.f;
        for (int k = 0; k < 128; k++) s += ctx[tid][k] * aw[k];
        lg[tid] = s + attn_b[0];
    }
    __syncthreads();

    if (tid < 64) {
        float v = (tid < CTXL) ? lg[tid] : -INFINITY;
        float m = v;
        for (int off = 32; off; off >>= 1) m = fmaxf(m, __shfl_xor(m, off));
        float e = (tid < CTXL) ? expf(v - m) : 0.f;
        float s = e;
        for (int off = 32; off; off >>= 1) s += __shfl_xor(s, off);
        if (tid < CTXL) lg[tid] = e / s;
    }
    __syncthreads();

    if (tid < 128) {
        float s = 0.f;
        for (int t = 0; t < CTXL; t++) s += lg[t] * ctx[t][tid];
        qin[tid] = s;
    }
    int mid = miss_ids[b];
    if (tid < 128) {
        cat[tid] = emb_table[(size_t)mid * DIM + tid];
    } else {
        int d = tid - 128;
        int fg = vocab_to_fg[mid];
        cat[tid] = (fg >= 0) ? graph[(size_t)fg * DIM + d] : 0.f;
    }
    __syncthreads();

    if (tid < 128) {
        float s = fusion_b[tid];
        const float4* wr = reinterpret_cast<const float4*>(fusion_w + (size_t)tid * 256);
        const float4* cr = reinterpret_cast<const float4*>(cat);
        for (int k = 0; k < 64; k++) {
            float4 w4 = wr[k];
            float4 c4 = cr[k];
            s += w4.x * c4.x + w4.y * c4.y + w4.z * c4.z + w4.w * c4.w;
        }
        qin[128 + tid] = s;
    }
    __syncthreads();

    {
        float s = proj1_b[tid];
        const float4* wr = reinterpret_cast<const float4*>(proj1_w + (size_t)tid * 256);
        const float4* cr = reinterpret_cast<const float4*>(qin);
        for (int k = 0; k < 64; k++) {
            float4 w4 = wr[k];
            float4 c4 = cr[k];
            s += w4.x * c4.x + w4.y * c4.y + w4.z * c4.z + w4.w * c4.w;
        }
        q1[tid] = fmaxf(s, 0.f);
    }
    __syncthreads();

    if (tid < 128) {
        float s = proj2_b[tid];
        const float4* wr = reinterpret_cast<const float4*>(proj2_w + (size_t)tid * 256);
        const float4* cr = reinterpret_cast<const float4*>(q1);
        for (int k = 0; k < 64; k++) {
            float4 w4 = wr[k];
            float4 c4 = cr[k];
            s += w4.x * c4.x + w4.y * c4.y + w4.z * c4.z + w4.w * c4.w;
        }
        query[(size_t)b * DIM + tid] = s;
    }
}

extern "C" void kernel_launch(void* const* d_in, const int* in_sizes, int n_in,
                              void* d_out, int out_size, void* d_ws, size_t ws_size,
                              hipStream_t stream) {
    const int*   edge_index = (const int*)d_in[0];
    const float* norm       = (const float*)d_in[1];
    const int*   ctx_ids    = (const int*)d_in[2];
    const int*   miss_ids   = (const int*)d_in[3];
    const int*   vocab_to_fg= (const int*)d_in[4];
    const float* emb_table  = (const float*)d_in[5];
    const float* fg_emb     = (const float*)d_in[6];
    const float* gc_w       = (const float*)d_in[7];
    const float* bn_gamma   = (const float*)d_in[8];
    const float* bn_beta    = (const float*)d_in[9];
    const float* attn_w     = (const float*)d_in[10];
    const float* attn_b     = (const float*)d_in[11];
    const float* fusion_w   = (const float*)d_in[12];
    const float* fusion_b   = (const float*)d_in[13];
    const float* proj1_w    = (const float*)d_in[14];
    const float* proj1_b    = (const float*)d_in[15];
    const float* proj2_w    = (const float*)d_in[16];
    const float* proj2_b    = (const float*)d_in[17];

    const int* row = edge_index;
    const int* col = edge_index + NE;

    float* ws = (float*)d_ws;
    float*          z      = ws + OFF_Z;
    unsigned short* Ah     = (unsigned short*)(ws + OFF_AH);
    unsigned short* hbf    = (unsigned short*)(ws + OFF_HBF);
    float*          edge_s = ws + OFF_EDG;
    int*   row_start = (int*)(ws + OFF_RS);
    int*   cursor    = (int*)(ws + OFF_CUR);
    int*   counts    = (int*)(ws + OFF_CNT);
    float* stats     = ws + OFF_STAT;
    float* scsh      = ws + OFF_SCSH;
    unsigned short* Wh = (unsigned short*)(ws + OFF_WH);
    unsigned short* Wl = (unsigned short*)(ws + OFF_WL);

    float* query = (float*)d_out;
    float* G     = (float*)d_out + (size_t)NB * DIM;  // graph_embs, doubles as h

    hipMemsetAsync(counts, 0, NN * sizeof(int), stream);
    hipMemsetAsync(stats, 0, 256 * sizeof(float), stream);

    const int EB = (NE + 255) / 256;  // 3125
    wsplit_kernel<<<128, 256, 0, stream>>>(gc_w, Wh, Wl);
    cast_bf_kernel<<<6250, 256, 0, stream>>>(fg_emb, hbf);
    hist_kernel<<<EB, 256, 0, stream>>>(row, counts);
    scan_kernel<<<1, 1024, 0, stream>>>(counts, row_start, cursor);
    scatter_kernel<<<EB, 256, 0, stream>>>(row, col, norm, cursor, edge_s);

    const int AGG_B = NN / 4;                 // 12500 blocks, one wave per row
    const int RES_B = (NN * DIM / 4) / 256;   // 6250
    dim3 gemm_grid(196, 4);                   // 784 blocks; y = 32-channel group

    // ---- layer 1 ----
    agg_bf_kernel<<<AGG_B, 256, 0, stream>>>(hbf, row_start, edge_s, Ah);
    gemm_mfma_kernel<<<gemm_grid, 256, 0, stream>>>(Ah, Wh, Wl, z, stats);
    bn_finalize_kernel<<<1, 128, 0, stream>>>(stats, bn_gamma, bn_beta, scsh);
    residual_kernel<<<RES_B, 256, 0, stream>>>(fg_emb, z, scsh, G, hbf);

    // ---- layer 2 ----
    agg_bf_kernel<<<AGG_B, 256, 0, stream>>>(hbf, row_start, edge_s, Ah);
    gemm_mfma_kernel<<<gemm_grid, 256, 0, stream>>>(Ah, Wh + DIM * DIM, Wl + DIM * DIM, z, stats);
    bn_finalize_kernel<<<1, 128, 0, stream>>>(stats, bn_gamma + 128, bn_beta + 128, scsh);
    residual_kernel<<<RES_B, 256, 0, stream>>>(G, z, scsh, G, nullptr);

    // ---- batch head ----
    batch_kernel<<<NB, 256, 0, stream>>>(ctx_ids, miss_ids, vocab_to_fg, emb_table, G,
                                         attn_w, attn_b, fusion_w, fusion_b,
                                         proj1_w, proj1_b, proj2_w, proj2_b, query);
}

// Round 4
// 517.244 us; speedup vs baseline: 1.7493x; 1.2142x over previous
//
#include <hip/hip_runtime.h>

#define NN 50000
#define NE 800000
#define DIM 128
#define NB 1024
#define CTXL 50
#define BN_EPS 1e-5f
#define STRIPS 3125   // NN/16
#define SCAN_B 196    // ceil(NN/256)

// ---------------- ws layout (float offsets) ----------------
static const size_t OFF_Z    = 0;          // z fp32 [NN][128]          25.6 MB
static const size_t OFF_AH   = 6400000;    // Ah bf16 [NN][128]         12.8 MB
static const size_t OFF_HBF  = 9600000;    // hbf bf16 [NN][128]        12.8 MB (fgbf then Gbf)
static const size_t OFF_EDG  = 12800000;   // (col,norm) pairs [NE][2]   6.4 MB
static const size_t OFF_RS   = 14400000;   // row_start [NN+1] int
static const size_t OFF_CUR  = 14450048;   // cursor [NN] int
static const size_t OFF_CNT  = 14500096;   // counts [NN] int
static const size_t OFF_STAT = 14550144;   // stats [256] f
static const size_t OFF_SCSH = 14550400;   // scale/shift [256] f
static const size_t OFF_WH   = 14550656;   // Wh bf16 [2][128][128]
static const size_t OFF_WL   = 14567040;   // Wl bf16 [2][128][128]
static const size_t OFF_BS   = 14583424;   // bsums [256] int
static const size_t OFF_BO   = 14583680;   // boffs [256] int

typedef __attribute__((ext_vector_type(8))) short s16x8;
typedef __attribute__((ext_vector_type(4))) float fx4;

__device__ __forceinline__ unsigned short f2bf(float f) {
    unsigned u = __float_as_uint(f);
    unsigned r = u + 0x7FFFu + ((u >> 16) & 1u);
    return (unsigned short)(r >> 16);
}
__device__ __forceinline__ float bf2f(unsigned short b) {
    return __uint_as_float((unsigned)b << 16);
}

// ---------------- CSR build ----------------
__global__ void hist_kernel(const int* __restrict__ row, int* __restrict__ counts) {
    int e = blockIdx.x * 256 + threadIdx.x;
    if (e < NE) atomicAdd(&counts[row[e]], 1);
}

// ---- 3-phase parallel exclusive scan over counts[NN] ----
__global__ __launch_bounds__(256) void scan_blocksums(const int* __restrict__ counts,
                                                      int* __restrict__ bsums) {
    __shared__ int red[4];
    int i = blockIdx.x * 256 + threadIdx.x;
    int v = (i < NN) ? counts[i] : 0;
    #pragma unroll
    for (int off = 32; off; off >>= 1) v += __shfl_down(v, off);
    if ((threadIdx.x & 63) == 0) red[threadIdx.x >> 6] = v;
    __syncthreads();
    if (threadIdx.x == 0) bsums[blockIdx.x] = red[0] + red[1] + red[2] + red[3];
}

__global__ __launch_bounds__(256) void scan_bsums(const int* __restrict__ bsums,
                                                  int* __restrict__ boffs) {
    __shared__ int lds[256];
    int t = threadIdx.x;
    lds[t] = (t < SCAN_B) ? bsums[t] : 0;
    __syncthreads();
    for (int off = 1; off < 256; off <<= 1) {
        int add = (t >= off) ? lds[t - off] : 0;
        __syncthreads();
        lds[t] += add;
        __syncthreads();
    }
    boffs[t] = (t == 0) ? 0 : lds[t - 1];
}

__global__ __launch_bounds__(256) void scan_final(const int* __restrict__ counts,
                                                  const int* __restrict__ boffs,
                                                  int* __restrict__ row_start,
                                                  int* __restrict__ cursor) {
    __shared__ int lds[256];
    int t = threadIdx.x;
    int i = blockIdx.x * 256 + t;
    int v = (i < NN) ? counts[i] : 0;
    lds[t] = v;
    __syncthreads();
    for (int off = 1; off < 256; off <<= 1) {
        int add = (t >= off) ? lds[t - off] : 0;
        __syncthreads();
        lds[t] += add;
        __syncthreads();
    }
    int excl = boffs[blockIdx.x] + ((t == 0) ? 0 : lds[t - 1]);
    if (i < NN) {
        row_start[i] = excl;
        cursor[i] = excl;
    }
    if (i == 0) row_start[NN] = NE;  // total is a constant
}

__global__ void scatter_kernel(const int* __restrict__ row, const int* __restrict__ col,
                               const float* __restrict__ norm, int* __restrict__ cursor,
                               float* __restrict__ edge_s) {
    int e = blockIdx.x * 256 + threadIdx.x;
    if (e < NE) {
        int r = row[e];
        int p = atomicAdd(&cursor[r], 1);
        ((int*)edge_s)[2 * p] = col[e];
        edge_s[2 * p + 1] = norm[e];
    }
}

// ---------------- prep: W split, h cast ----------------
__global__ void wsplit_kernel(const float* __restrict__ W, unsigned short* __restrict__ Wh,
                              unsigned short* __restrict__ Wl) {
    int i = blockIdx.x * 256 + threadIdx.x;
    if (i < 2 * DIM * DIM) {
        float v = W[i];
        unsigned short h = f2bf(v);
        Wh[i] = h;
        Wl[i] = f2bf(v - bf2f(h));
    }
}

__global__ void cast_bf_kernel(const float* __restrict__ in, unsigned short* __restrict__ out) {
    int i = blockIdx.x * 256 + threadIdx.x;  // float4 index
    if (i >= NN * DIM / 4) return;
    float4 v = reinterpret_cast<const float4*>(in)[i];
    ushort4 o = make_ushort4(f2bf(v.x), f2bf(v.y), f2bf(v.z), f2bf(v.w));
    reinterpret_cast<ushort4*>(out)[i] = o;
}

// ---------------- aggregation: one wave per row, gather bf16 rows, fp32 accum ----------------
__global__ __launch_bounds__(256) void agg_bf_kernel(const unsigned short* __restrict__ hbf,
                                                     const int* __restrict__ row_start,
                                                     const float* __restrict__ edge_s,
                                                     unsigned short* __restrict__ Ah) {
    int gw = (blockIdx.x * 256 + threadIdx.x) >> 6;
    int lane = threadIdx.x & 63;
    if (gw >= NN) return;
    int s = row_start[gw];
    int e = row_start[gw + 1];
    const int2* ep = (const int2*)edge_s;
    float ax = 0.f, ay = 0.f;
    int j = s;
    for (; j + 4 <= e; j += 4) {
        int2 p0 = ep[j], p1 = ep[j + 1], p2 = ep[j + 2], p3 = ep[j + 3];
        ushort2 v0 = *(const ushort2*)(hbf + (size_t)p0.x * DIM + lane * 2);
        ushort2 v1 = *(const ushort2*)(hbf + (size_t)p1.x * DIM + lane * 2);
        ushort2 v2 = *(const ushort2*)(hbf + (size_t)p2.x * DIM + lane * 2);
        ushort2 v3 = *(const ushort2*)(hbf + (size_t)p3.x * DIM + lane * 2);
        float w0 = __int_as_float(p0.y), w1 = __int_as_float(p1.y);
        float w2 = __int_as_float(p2.y), w3 = __int_as_float(p3.y);
        ax = fmaf(w0, bf2f(v0.x), ax); ay = fmaf(w0, bf2f(v0.y), ay);
        ax = fmaf(w1, bf2f(v1.x), ax); ay = fmaf(w1, bf2f(v1.y), ay);
        ax = fmaf(w2, bf2f(v2.x), ax); ay = fmaf(w2, bf2f(v2.y), ay);
        ax = fmaf(w3, bf2f(v3.x), ax); ay = fmaf(w3, bf2f(v3.y), ay);
    }
    for (; j < e; j++) {
        int2 p = ep[j];
        ushort2 v = *(const ushort2*)(hbf + (size_t)p.x * DIM + lane * 2);
        float w = __int_as_float(p.y);
        ax = fmaf(w, bf2f(v.x), ax); ay = fmaf(w, bf2f(v.y), ay);
    }
    *(ushort2*)(Ah + (size_t)gw * DIM + lane * 2) = make_ushort2(f2bf(ax), f2bf(ay));
}

// ---------------- z = relu(agg @ W^T) via MFMA, W register-resident (32 channels/wave) ----------------
__global__ __launch_bounds__(256) void gemm_mfma_kernel(const unsigned short* __restrict__ Ah,
                                                        const unsigned short* __restrict__ Wh,
                                                        const unsigned short* __restrict__ Wl,
                                                        float* __restrict__ z,
                                                        float* __restrict__ stats) {
    int lane = threadIdx.x & 63;
    int r16 = lane & 15;
    int kg = lane >> 4;
    int cq = blockIdx.y;                       // 32-channel group, 0..3
    int wv = (blockIdx.x * 256 + threadIdx.x) >> 6;
    int nw = gridDim.x * 4;

    s16x8 wf[2][4][2];  // [ctile][kstep][hi/lo] = 64 VGPRs
    #pragma unroll
    for (int ct = 0; ct < 2; ct++) {
        #pragma unroll
        for (int ks = 0; ks < 4; ks++) {
            size_t off = (size_t)(cq * 32 + ct * 16 + r16) * DIM + ks * 32 + kg * 8;
            wf[ct][ks][0] = *(const s16x8*)(Wh + off);
            wf[ct][ks][1] = *(const s16x8*)(Wl + off);
        }
    }

    float bsum[2][4] = {{0.f}}, bsq[2][4] = {{0.f}};

    for (int strip = wv; strip < STRIPS; strip += nw) {
        size_t abase = (size_t)(strip * 16 + r16) * DIM + kg * 8;
        fx4 acc[2];
        acc[0] = (fx4){0.f, 0.f, 0.f, 0.f};
        acc[1] = (fx4){0.f, 0.f, 0.f, 0.f};
        #pragma unroll
        for (int ks = 0; ks < 4; ks++) {
            s16x8 b = *(const s16x8*)(Ah + abase + ks * 32);
            #pragma unroll
            for (int ct = 0; ct < 2; ct++) {
                acc[ct] = __builtin_amdgcn_mfma_f32_16x16x32_bf16(wf[ct][ks][0], b, acc[ct], 0, 0, 0);
                acc[ct] = __builtin_amdgcn_mfma_f32_16x16x32_bf16(wf[ct][ks][1], b, acc[ct], 0, 0, 0);
            }
        }
        size_t zrow = (size_t)(strip * 16 + r16) * DIM + cq * 32 + kg * 4;
        #pragma unroll
        for (int ct = 0; ct < 2; ct++) {
            float4 o;
            o.x = fmaxf(acc[ct][0], 0.f);
            o.y = fmaxf(acc[ct][1], 0.f);
            o.z = fmaxf(acc[ct][2], 0.f);
            o.w = fmaxf(acc[ct][3], 0.f);
            bsum[ct][0] += o.x; bsq[ct][0] += o.x * o.x;
            bsum[ct][1] += o.y; bsq[ct][1] += o.y * o.y;
            bsum[ct][2] += o.z; bsq[ct][2] += o.z * o.z;
            bsum[ct][3] += o.w; bsq[ct][3] += o.w * o.w;
            *(float4*)(z + zrow + ct * 16) = o;
        }
    }

    #pragma unroll
    for (int ct = 0; ct < 2; ct++) {
        #pragma unroll
        for (int jj = 0; jj < 4; jj++) {
            float s = bsum[ct][jj], q = bsq[ct][jj];
            #pragma unroll
            for (int off = 1; off <= 8; off <<= 1) {
                s += __shfl_xor(s, off);
                q += __shfl_xor(q, off);
            }
            if (r16 == 0) {
                int c = cq * 32 + ct * 16 + kg * 4 + jj;
                unsafeAtomicAdd(&stats[c], s);
                unsafeAtomicAdd(&stats[128 + c], q);
            }
        }
    }
}

__global__ void bn_finalize_kernel(float* __restrict__ stats, const float* __restrict__ gamma,
                                   const float* __restrict__ beta, float* __restrict__ scsh) {
    int c = threadIdx.x;
    if (c < 128) {
        float mu = stats[c] * (1.f / (float)NN);
        float ex2 = stats[128 + c] * (1.f / (float)NN);
        float var = ex2 - mu * mu;
        float sc = gamma[c] / sqrtf(var + BN_EPS);
        scsh[c] = sc;
        scsh[128 + c] = beta[c] - mu * sc;
        stats[c] = 0.f;  // reset for next layer
        stats[128 + c] = 0.f;
    }
}

// ---------------- h_out = h_in + z*scale + shift (+ optional bf16 emit) ----------------
__global__ __launch_bounds__(256) void residual_kernel(const float* hin,
                                                       const float* z,
                                                       const float* __restrict__ scsh,
                                                       float* hout,
                                                       unsigned short* hbf_out) {
    int i = blockIdx.x * 256 + threadIdx.x;  // float4 index
    if (i >= NN * DIM / 4) return;
    int c = (i * 4) & 127;
    float4 zv = reinterpret_cast<const float4*>(z)[i];
    float4 hv = reinterpret_cast<const float4*>(hin)[i];
    float4 sc = *reinterpret_cast<const float4*>(scsh + c);
    float4 sh = *reinterpret_cast<const float4*>(scsh + 128 + c);
    float4 o;
    o.x = hv.x + zv.x * sc.x + sh.x;
    o.y = hv.y + zv.y * sc.y + sh.y;
    o.z = hv.z + zv.z * sc.z + sh.z;
    o.w = hv.w + zv.w * sc.w + sh.w;
    reinterpret_cast<float4*>(hout)[i] = o;
    if (hbf_out) {
        ushort4 ob = make_ushort4(f2bf(o.x), f2bf(o.y), f2bf(o.z), f2bf(o.w));
        reinterpret_cast<ushort4*>(hbf_out)[i] = ob;
    }
}

// ---------------- fused batch head ----------------
__global__ __launch_bounds__(256) void batch_kernel(const int* __restrict__ ctx_ids,
                                                    const int* __restrict__ miss_ids,
                                                    const int* __restrict__ vocab_to_fg,
                                                    const float* __restrict__ emb_table,
                                                    const float* __restrict__ graph,
                                                    const float* __restrict__ attn_w,
                                                    const float* __restrict__ attn_b,
                                                    const float* __restrict__ fusion_w,
                                                    const float* __restrict__ fusion_b,
                                                    const float* __restrict__ proj1_w,
                                                    const float* __restrict__ proj1_b,
                                                    const float* __restrict__ proj2_w,
                                                    const float* __restrict__ proj2_b,
                                                    float* __restrict__ query) {
    int b = blockIdx.x;
    int tid = threadIdx.x;
    __shared__ float ctx[CTXL][129];
    __shared__ float aw[128];
    __shared__ float lg[64];
    __shared__ __align__(16) float qin[256];
    __shared__ __align__(16) float cat[256];
    __shared__ __align__(16) float q1[256];

    if (tid < 128) aw[tid] = attn_w[tid];
    for (int f = tid; f < CTXL * 128; f += 256) {
        int t = f >> 7, d = f & 127;
        int vid = ctx_ids[b * CTXL + t];
        ctx[t][d] = emb_table[(size_t)vid * DIM + d];
    }
    __syncthreads();

    if (tid < CTXL) {
        float s = 0.f;
        for (int k = 0; k < 128; k++) s += ctx[tid][k] * aw[k];
        lg[tid] = s + attn_b[0];
    }
    __syncthreads();

    if (tid < 64) {
        float v = (tid < CTXL) ? lg[tid] : -INFINITY;
        float m = v;
        for (int off = 32; off; off >>= 1) m = fmaxf(m, __shfl_xor(m, off));
        float e = (tid < CTXL) ? expf(v - m) : 0.f;
        float s = e;
        for (int off = 32; off; off >>= 1) s += __shfl_xor(s, off);
        if (tid < CTXL) lg[tid] = e / s;
    }
    __syncthreads();

    if (tid < 128) {
        float s = 0.f;
        for (int t = 0; t < CTXL; t++) s += lg[t] * ctx[t][tid];
        qin[tid] = s;
    }
    int mid = miss_ids[b];
    if (tid < 128) {
        cat[tid] = emb_table[(size_t)mid * DIM + tid];
    } else {
        int d = tid - 128;
        int fg = vocab_to_fg[mid];
        cat[tid] = (fg >= 0) ? graph[(size_t)fg * DIM + d] : 0.f;
    }
    __syncthreads();

    if (tid < 128) {
        float s = fusion_b[tid];
        const float4* wr = reinterpret_cast<const float4*>(fusion_w + (size_t)tid * 256);
        const float4* cr = reinterpret_cast<const float4*>(cat);
        for (int k = 0; k < 64; k++) {
            float4 w4 = wr[k];
            float4 c4 = cr[k];
            s += w4.x * c4.x + w4.y * c4.y + w4.z * c4.z + w4.w * c4.w;
        }
        qin[128 + tid] = s;
    }
    __syncthreads();

    {
        float s = proj1_b[tid];
        const float4* wr = reinterpret_cast<const float4*>(proj1_w + (size_t)tid * 256);
        const float4* cr = reinterpret_cast<const float4*>(qin);
        for (int k = 0; k < 64; k++) {
            float4 w4 = wr[k];
            float4 c4 = cr[k];
            s += w4.x * c4.x + w4.y * c4.y + w4.z * c4.z + w4.w * c4.w;
        }
        q1[tid] = fmaxf(s, 0.f);
    }
    __syncthreads();

    if (tid < 128) {
        float s = proj2_b[tid];
        const float4* wr = reinterpret_cast<const float4*>(proj2_w + (size_t)tid * 256);
        const float4* cr = reinterpret_cast<const float4*>(q1);
        for (int k = 0; k < 64; k++) {
            float4 w4 = wr[k];
            float4 c4 = cr[k];
            s += w4.x * c4.x + w4.y * c4.y + w4.z * c4.z + w4.w * c4.w;
        }
        query[(size_t)b * DIM + tid] = s;
    }
}

extern "C" void kernel_launch(void* const* d_in, const int* in_sizes, int n_in,
                              void* d_out, int out_size, void* d_ws, size_t ws_size,
                              hipStream_t stream) {
    const int*   edge_index = (const int*)d_in[0];
    const float* norm       = (const float*)d_in[1];
    const int*   ctx_ids    = (const int*)d_in[2];
    const int*   miss_ids   = (const int*)d_in[3];
    const int*   vocab_to_fg= (const int*)d_in[4];
    const float* emb_table  = (const float*)d_in[5];
    const float* fg_emb     = (const float*)d_in[6];
    const float* gc_w       = (const float*)d_in[7];
    const float* bn_gamma   = (const float*)d_in[8];
    const float* bn_beta    = (const float*)d_in[9];
    const float* attn_w     = (const float*)d_in[10];
    const float* attn_b     = (const float*)d_in[11];
    const float* fusion_w   = (const float*)d_in[12];
    const float* fusion_b   = (const float*)d_in[13];
    const float* proj1_w    = (const float*)d_in[14];
    const float* proj1_b    = (const float*)d_in[15];
    const float* proj2_w    = (const float*)d_in[16];
    const float* proj2_b    = (const float*)d_in[17];

    const int* row = edge_index;
    const int* col = edge_index + NE;

    float* ws = (float*)d_ws;
    float*          z      = ws + OFF_Z;
    unsigned short* Ah     = (unsigned short*)(ws + OFF_AH);
    unsigned short* hbf    = (unsigned short*)(ws + OFF_HBF);
    float*          edge_s = ws + OFF_EDG;
    int*   row_start = (int*)(ws + OFF_RS);
    int*   cursor    = (int*)(ws + OFF_CUR);
    int*   counts    = (int*)(ws + OFF_CNT);
    float* stats     = ws + OFF_STAT;
    float* scsh      = ws + OFF_SCSH;
    unsigned short* Wh = (unsigned short*)(ws + OFF_WH);
    unsigned short* Wl = (unsigned short*)(ws + OFF_WL);
    int*   bsums     = (int*)(ws + OFF_BS);
    int*   boffs     = (int*)(ws + OFF_BO);

    float* query = (float*)d_out;
    float* G     = (float*)d_out + (size_t)NB * DIM;  // graph_embs, doubles as h

    hipMemsetAsync(counts, 0, NN * sizeof(int), stream);
    hipMemsetAsync(stats, 0, 256 * sizeof(float), stream);

    const int EB = (NE + 255) / 256;  // 3125
    wsplit_kernel<<<128, 256, 0, stream>>>(gc_w, Wh, Wl);
    cast_bf_kernel<<<6250, 256, 0, stream>>>(fg_emb, hbf);
    hist_kernel<<<EB, 256, 0, stream>>>(row, counts);
    scan_blocksums<<<SCAN_B, 256, 0, stream>>>(counts, bsums);
    scan_bsums<<<1, 256, 0, stream>>>(bsums, boffs);
    scan_final<<<SCAN_B, 256, 0, stream>>>(counts, boffs, row_start, cursor);
    scatter_kernel<<<EB, 256, 0, stream>>>(row, col, norm, cursor, edge_s);

    const int AGG_B = NN / 4;                 // 12500 blocks, one wave per row
    const int RES_B = (NN * DIM / 4) / 256;   // 6250
    dim3 gemm_grid(196, 4);                   // 784 blocks; y = 32-channel group

    // ---- layer 1 ----
    agg_bf_kernel<<<AGG_B, 256, 0, stream>>>(hbf, row_start, edge_s, Ah);
    gemm_mfma_kernel<<<gemm_grid, 256, 0, stream>>>(Ah, Wh, Wl, z, stats);
    bn_finalize_kernel<<<1, 128, 0, stream>>>(stats, bn_gamma, bn_beta, scsh);
    residual_kernel<<<RES_B, 256, 0, stream>>>(fg_emb, z, scsh, G, hbf);

    // ---- layer 2 ----
    agg_bf_kernel<<<AGG_B, 256, 0, stream>>>(hbf, row_start, edge_s, Ah);
    gemm_mfma_kernel<<<gemm_grid, 256, 0, stream>>>(Ah, Wh + DIM * DIM, Wl + DIM * DIM, z, stats);
    bn_finalize_kernel<<<1, 128, 0, stream>>>(stats, bn_gamma + 128, bn_beta + 128, scsh);
    residual_kernel<<<RES_B, 256, 0, stream>>>(G, z, scsh, G, nullptr);

    // ---- batch head ----
    batch_kernel<<<NB, 256, 0, stream>>>(ctx_ids, miss_ids, vocab_to_fg, emb_table, G,
                                         attn_w, attn_b, fusion_w, fusion_b,
                                         proj1_w, proj1_b, proj2_w, proj2_b, query);
}

// Round 6
// 489.773 us; speedup vs baseline: 1.8474x; 1.0561x over previous
//
#include <hip/hip_runtime.h>

#define NN 50000
#define NE 800000
#define DIM 128
#define NB 1024
#define CTXL 50
#define BN_EPS 1e-5f
#define STRIPS 3125   // NN/16
#define SCAN_B 196    // ceil(NN/256)

// ---------------- ws layout (float offsets) ----------------
static const size_t OFF_Z    = 0;          // z fp32 [NN][128]          25.6 MB
static const size_t OFF_AH   = 6400000;    // Ah bf16 [NN][128]         12.8 MB
static const size_t OFF_HBF  = 9600000;    // hbf bf16 [NN][128]        12.8 MB (fgbf then Gbf)
static const size_t OFF_EDG  = 12800000;   // (col,norm) pairs [NE][2]   6.4 MB
static const size_t OFF_RS   = 14400000;   // row_start [NN+1] int
static const size_t OFF_CUR  = 14450048;   // cursor [NN] int
static const size_t OFF_CNT  = 14500096;   // counts [NN] int
static const size_t OFF_STAT = 14550144;   // stats [256] f
static const size_t OFF_SCSH = 14550400;   // scale/shift [256] f
static const size_t OFF_WH   = 14550656;   // Wh bf16 [2][128][128]
static const size_t OFF_WL   = 14567040;   // Wl bf16 [2][128][128]
static const size_t OFF_BS   = 14583424;   // bsums [256] int
static const size_t OFF_BO   = 14583680;   // boffs [256] int

typedef __attribute__((ext_vector_type(8))) short s16x8;
typedef __attribute__((ext_vector_type(4))) float fx4;

__device__ __forceinline__ unsigned short f2bf(float f) {
    unsigned u = __float_as_uint(f);
    unsigned r = u + 0x7FFFu + ((u >> 16) & 1u);
    return (unsigned short)(r >> 16);
}
__device__ __forceinline__ float bf2f(unsigned short b) {
    return __uint_as_float((unsigned)b << 16);
}

// ---------------- CSR build ----------------
__global__ void hist_kernel(const int* __restrict__ row, int* __restrict__ counts) {
    int e = blockIdx.x * 256 + threadIdx.x;
    if (e < NE) atomicAdd(&counts[row[e]], 1);
}

__global__ __launch_bounds__(256) void scan_blocksums(const int* __restrict__ counts,
                                                      int* __restrict__ bsums) {
    __shared__ int red[4];
    int i = blockIdx.x * 256 + threadIdx.x;
    int v = (i < NN) ? counts[i] : 0;
    #pragma unroll
    for (int off = 32; off; off >>= 1) v += __shfl_down(v, off);
    if ((threadIdx.x & 63) == 0) red[threadIdx.x >> 6] = v;
    __syncthreads();
    if (threadIdx.x == 0) bsums[blockIdx.x] = red[0] + red[1] + red[2] + red[3];
}

__global__ __launch_bounds__(256) void scan_bsums(const int* __restrict__ bsums,
                                                  int* __restrict__ boffs) {
    __shared__ int lds[256];
    int t = threadIdx.x;
    lds[t] = (t < SCAN_B) ? bsums[t] : 0;
    __syncthreads();
    for (int off = 1; off < 256; off <<= 1) {
        int add = (t >= off) ? lds[t - off] : 0;
        __syncthreads();
        lds[t] += add;
        __syncthreads();
    }
    boffs[t] = (t == 0) ? 0 : lds[t - 1];
}

__global__ __launch_bounds__(256) void scan_final(const int* __restrict__ counts,
                                                  const int* __restrict__ boffs,
                                                  int* __restrict__ row_start,
                                                  int* __restrict__ cursor) {
    __shared__ int lds[256];
    int t = threadIdx.x;
    int i = blockIdx.x * 256 + t;
    int v = (i < NN) ? counts[i] : 0;
    lds[t] = v;
    __syncthreads();
    for (int off = 1; off < 256; off <<= 1) {
        int add = (t >= off) ? lds[t - off] : 0;
        __syncthreads();
        lds[t] += add;
        __syncthreads();
    }
    int excl = boffs[blockIdx.x] + ((t == 0) ? 0 : lds[t - 1]);
    if (i < NN) {
        row_start[i] = excl;
        cursor[i] = excl;
    }
    if (i == 0) row_start[NN] = NE;
}

__global__ void scatter_kernel(const int* __restrict__ row, const int* __restrict__ col,
                               const float* __restrict__ norm, int* __restrict__ cursor,
                               float* __restrict__ edge_s) {
    int e = blockIdx.x * 256 + threadIdx.x;
    if (e < NE) {
        int r = row[e];
        int p = atomicAdd(&cursor[r], 1);
        ((int*)edge_s)[2 * p] = col[e];
        edge_s[2 * p + 1] = norm[e];
    }
}

// ---------------- prep: W split, h cast ----------------
__global__ void wsplit_kernel(const float* __restrict__ W, unsigned short* __restrict__ Wh,
                              unsigned short* __restrict__ Wl) {
    int i = blockIdx.x * 256 + threadIdx.x;
    if (i < 2 * DIM * DIM) {
        float v = W[i];
        unsigned short h = f2bf(v);
        Wh[i] = h;
        Wl[i] = f2bf(v - bf2f(h));
    }
}

__global__ void cast_bf_kernel(const float* __restrict__ in, unsigned short* __restrict__ out) {
    int i = blockIdx.x * 256 + threadIdx.x;  // float4 index
    if (i >= NN * DIM / 4) return;
    float4 v = reinterpret_cast<const float4*>(in)[i];
    ushort4 o = make_ushort4(f2bf(v.x), f2bf(v.y), f2bf(v.z), f2bf(v.w));
    reinterpret_cast<ushort4*>(out)[i] = o;
}

// ---------------- aggregation: one wave per row, gather bf16 rows, fp32 accum ----------------
__global__ __launch_bounds__(256) void agg_bf_kernel(const unsigned short* __restrict__ hbf,
                                                     const int* __restrict__ row_start,
                                                     const float* __restrict__ edge_s,
                                                     unsigned short* __restrict__ Ah) {
    int gw = (blockIdx.x * 256 + threadIdx.x) >> 6;
    int lane = threadIdx.x & 63;
    if (gw >= NN) return;
    int s = row_start[gw];
    int e = row_start[gw + 1];
    const int2* ep = (const int2*)edge_s;
    float ax = 0.f, ay = 0.f;
    int j = s;
    for (; j + 4 <= e; j += 4) {
        int2 p0 = ep[j], p1 = ep[j + 1], p2 = ep[j + 2], p3 = ep[j + 3];
        ushort2 v0 = *(const ushort2*)(hbf + (size_t)p0.x * DIM + lane * 2);
        ushort2 v1 = *(const ushort2*)(hbf + (size_t)p1.x * DIM + lane * 2);
        ushort2 v2 = *(const ushort2*)(hbf + (size_t)p2.x * DIM + lane * 2);
        ushort2 v3 = *(const ushort2*)(hbf + (size_t)p3.x * DIM + lane * 2);
        float w0 = __int_as_float(p0.y), w1 = __int_as_float(p1.y);
        float w2 = __int_as_float(p2.y), w3 = __int_as_float(p3.y);
        ax = fmaf(w0, bf2f(v0.x), ax); ay = fmaf(w0, bf2f(v0.y), ay);
        ax = fmaf(w1, bf2f(v1.x), ax); ay = fmaf(w1, bf2f(v1.y), ay);
        ax = fmaf(w2, bf2f(v2.x), ax); ay = fmaf(w2, bf2f(v2.y), ay);
        ax = fmaf(w3, bf2f(v3.x), ax); ay = fmaf(w3, bf2f(v3.y), ay);
    }
    for (; j < e; j++) {
        int2 p = ep[j];
        ushort2 v = *(const ushort2*)(hbf + (size_t)p.x * DIM + lane * 2);
        float w = __int_as_float(p.y);
        ax = fmaf(w, bf2f(v.x), ax); ay = fmaf(w, bf2f(v.y), ay);
    }
    *(ushort2*)(Ah + (size_t)gw * DIM + lane * 2) = make_ushort2(f2bf(ax), f2bf(ay));
}

// ---------------- z = relu(agg @ W^T) via MFMA, W staged in LDS ----------------
// blockIdx.y = cq selects 32 channels. W (hi+lo planes, 32x128 each, 16 KB) staged to LDS
// with XOR chunk swizzle: Wlds[plane][c][ (ck ^ (c&7))*8 .. +8 ] = W[cq*32+c][ck*8 .. +8].
// Fragment ds_read reads chunk (ks*4+kg) ^ (r16&7) -> even bank distribution.
// A fragments read directly from global per lane (proven-correct r4 path).
__global__ __launch_bounds__(256) void gemm_mfma_kernel(const unsigned short* __restrict__ Ah,
                                                        const unsigned short* __restrict__ Wh,
                                                        const unsigned short* __restrict__ Wl,
                                                        float* __restrict__ z,
                                                        float* __restrict__ stats) {
    __shared__ __align__(16) short Wlds[2][32][128];  // 16 KB
    int tid = threadIdx.x;
    int lane = tid & 63;
    int r16 = lane & 15;
    int kg = lane >> 4;
    int cq = blockIdx.y;  // 0..3

    // stage W: 1024 16B-chunks, 4 per thread
    #pragma unroll
    for (int ff = 0; ff < 4; ff++) {
        int f = ff * 256 + tid;
        int plane = f >> 9;        // 0..1
        int c = (f >> 4) & 31;     // channel within cq group
        int ck = f & 15;           // 16B chunk within row
        const unsigned short* srcp = (plane ? Wl : Wh) + (size_t)(cq * 32 + c) * DIM + ck * 8;
        s16x8 v = *(const s16x8*)srcp;
        *(s16x8*)&Wlds[plane][c][(ck ^ (c & 7)) * 8] = v;
    }
    __syncthreads();

    int wv = (blockIdx.x * 256 + tid) >> 6;
    int nw = gridDim.x * 4;
    float bsum[2][4] = {{0.f}}, bsq[2][4] = {{0.f}};

    for (int strip = wv; strip < STRIPS; strip += nw) {
        size_t abase = (size_t)(strip * 16 + r16) * DIM + kg * 8;
        s16x8 b[4];
        #pragma unroll
        for (int ks = 0; ks < 4; ks++) b[ks] = *(const s16x8*)(Ah + abase + ks * 32);

        fx4 acc[2];
        acc[0] = (fx4){0.f, 0.f, 0.f, 0.f};
        acc[1] = (fx4){0.f, 0.f, 0.f, 0.f};
        #pragma unroll
        for (int ks = 0; ks < 4; ks++) {
            #pragma unroll
            for (int ct = 0; ct < 2; ct++) {
                int wrow = ct * 16 + r16;
                int wch = ((ks * 4 + kg) ^ (r16 & 7)) * 8;
                s16x8 wh8 = *(const s16x8*)&Wlds[0][wrow][wch];
                s16x8 wl8 = *(const s16x8*)&Wlds[1][wrow][wch];
                acc[ct] = __builtin_amdgcn_mfma_f32_16x16x32_bf16(wh8, b[ks], acc[ct], 0, 0, 0);
                acc[ct] = __builtin_amdgcn_mfma_f32_16x16x32_bf16(wl8, b[ks], acc[ct], 0, 0, 0);
            }
        }
        size_t zrow = (size_t)(strip * 16 + r16) * DIM + cq * 32 + kg * 4;
        #pragma unroll
        for (int ct = 0; ct < 2; ct++) {
            float4 o;
            o.x = fmaxf(acc[ct][0], 0.f);
            o.y = fmaxf(acc[ct][1], 0.f);
            o.z = fmaxf(acc[ct][2], 0.f);
            o.w = fmaxf(acc[ct][3], 0.f);
            bsum[ct][0] += o.x; bsq[ct][0] += o.x * o.x;
            bsum[ct][1] += o.y; bsq[ct][1] += o.y * o.y;
            bsum[ct][2] += o.z; bsq[ct][2] += o.z * o.z;
            bsum[ct][3] += o.w; bsq[ct][3] += o.w * o.w;
            *(float4*)(z + zrow + ct * 16) = o;
        }
    }

    // channel c = cq*32 + ct*16 + kg*4 + jj shared by 16 lanes differing in r16 (lane bits 0-3)
    #pragma unroll
    for (int ct = 0; ct < 2; ct++) {
        #pragma unroll
        for (int jj = 0; jj < 4; jj++) {
            float s = bsum[ct][jj], q = bsq[ct][jj];
            #pragma unroll
            for (int off = 1; off <= 8; off <<= 1) {
                s += __shfl_xor(s, off);
                q += __shfl_xor(q, off);
            }
            if (r16 == 0) {
                int c = cq * 32 + ct * 16 + kg * 4 + jj;
                unsafeAtomicAdd(&stats[c], s);
                unsafeAtomicAdd(&stats[128 + c], q);
            }
        }
    }
}

__global__ void bn_finalize_kernel(float* __restrict__ stats, const float* __restrict__ gamma,
                                   const float* __restrict__ beta, float* __restrict__ scsh) {
    int c = threadIdx.x;
    if (c < 128) {
        float mu = stats[c] * (1.f / (float)NN);
        float ex2 = stats[128 + c] * (1.f / (float)NN);
        float var = ex2 - mu * mu;
        float sc = gamma[c] / sqrtf(var + BN_EPS);
        scsh[c] = sc;
        scsh[128 + c] = beta[c] - mu * sc;
        stats[c] = 0.f;  // reset for next layer
        stats[128 + c] = 0.f;
    }
}

// ---------------- h_out = h_in + z*scale + shift (+ optional bf16 emit) ----------------
__global__ __launch_bounds__(256) void residual_kernel(const float* hin,
                                                       const float* z,
                                                       const float* __restrict__ scsh,
                                                       float* hout,
                                                       unsigned short* hbf_out) {
    int i = blockIdx.x * 256 + threadIdx.x;  // float4 index
    if (i >= NN * DIM / 4) return;
    int c = (i * 4) & 127;
    float4 zv = reinterpret_cast<const float4*>(z)[i];
    float4 hv = reinterpret_cast<const float4*>(hin)[i];
    float4 sc = *reinterpret_cast<const float4*>(scsh + c);
    float4 sh = *reinterpret_cast<const float4*>(scsh + 128 + c);
    float4 o;
    o.x = hv.x + zv.x * sc.x + sh.x;
    o.y = hv.y + zv.y * sc.y + sh.y;
    o.z = hv.z + zv.z * sc.z + sh.z;
    o.w = hv.w + zv.w * sc.w + sh.w;
    reinterpret_cast<float4*>(hout)[i] = o;
    if (hbf_out) {
        ushort4 ob = make_ushort4(f2bf(o.x), f2bf(o.y), f2bf(o.z), f2bf(o.w));
        reinterpret_cast<ushort4*>(hbf_out)[i] = ob;
    }
}

// ---------------- fused batch head ----------------
__global__ __launch_bounds__(256) void batch_kernel(const int* __restrict__ ctx_ids,
                                                    const int* __restrict__ miss_ids,
                                                    const int* __restrict__ vocab_to_fg,
                                                    const float* __restrict__ emb_table,
                                                    const float* __restrict__ graph,
                                                    const float* __restrict__ attn_w,
                                                    const float* __restrict__ attn_b,
                                                    const float* __restrict__ fusion_w,
                                                    const float* __restrict__ fusion_b,
                                                    const float* __restrict__ proj1_w,
                                                    const float* __restrict__ proj1_b,
                                                    const float* __restrict__ proj2_w,
                                                    const float* __restrict__ proj2_b,
                                                    float* __restrict__ query) {
    int b = blockIdx.x;
    int tid = threadIdx.x;
    __shared__ float ctx[CTXL][129];
    __shared__ float aw[128];
    __shared__ float lg[64];
    __shared__ __align__(16) float qin[256];
    __shared__ __align__(16) float cat[256];
    __shared__ __align__(16) float q1[256];

    if (tid < 128) aw[tid] = attn_w[tid];
    for (int f = tid; f < CTXL * 128; f += 256) {
        int t = f >> 7, d = f & 127;
        int vid = ctx_ids[b * CTXL + t];
        ctx[t][d] = emb_table[(size_t)vid * DIM + d];
    }
    __syncthreads();

    if (tid < CTXL) {
        float s = 0.f;
        for (int k = 0; k < 128; k++) s += ctx[tid][k] * aw[k];
        lg[tid] = s + attn_b[0];
    }
    __syncthreads();

    if (tid < 64) {
        float v = (tid < CTXL) ? lg[tid] : -INFINITY;
        float m = v;
        for (int off = 32; off; off >>= 1) m = fmaxf(m, __shfl_xor(m, off));
        float e = (tid < CTXL) ? expf(v - m) : 0.f;
        float s = e;
        for (int off = 32; off; off >>= 1) s += __shfl_xor(s, off);
        if (tid < CTXL) lg[tid] = e / s;
    }
    __syncthreads();

    if (tid < 128) {
        float s = 0.f;
        for (int t = 0; t < CTXL; t++) s += lg[t] * ctx[t][tid];
        qin[tid] = s;
    }
    int mid = miss_ids[b];
    if (tid < 128) {
        cat[tid] = emb_table[(size_t)mid * DIM + tid];
    } else {
        int d = tid - 128;
        int fg = vocab_to_fg[mid];
        cat[tid] = (fg >= 0) ? graph[(size_t)fg * DIM + d] : 0.f;
    }
    __syncthreads();

    if (tid < 128) {
        float s = fusion_b[tid];
        const float4* wr = reinterpret_cast<const float4*>(fusion_w + (size_t)tid * 256);
        const float4* cr = reinterpret_cast<const float4*>(cat);
        for (int k = 0; k < 64; k++) {
            float4 w4 = wr[k];
            float4 c4 = cr[k];
            s += w4.x * c4.x + w4.y * c4.y + w4.z * c4.z + w4.w * c4.w;
        }
        qin[128 + tid] = s;
    }
    __syncthreads();

    {
        float s = proj1_b[tid];
        const float4* wr = reinterpret_cast<const float4*>(proj1_w + (size_t)tid * 256);
        const float4* cr = reinterpret_cast<const float4*>(qin);
        for (int k = 0; k < 64; k++) {
            float4 w4 = wr[k];
            float4 c4 = cr[k];
            s += w4.x * c4.x + w4.y * c4.y + w4.z * c4.z + w4.w * c4.w;
        }
        q1[tid] = fmaxf(s, 0.f);
    }
    __syncthreads();

    if (tid < 128) {
        float s = proj2_b[tid];
        const float4* wr = reinterpret_cast<const float4*>(proj2_w + (size_t)tid * 256);
        const float4* cr = reinterpret_cast<const float4*>(q1);
        for (int k = 0; k < 64; k++) {
            float4 w4 = wr[k];
            float4 c4 = cr[k];
            s += w4.x * c4.x + w4.y * c4.y + w4.z * c4.z + w4.w * c4.w;
        }
        query[(size_t)b * DIM + tid] = s;
    }
}

extern "C" void kernel_launch(void* const* d_in, const int* in_sizes, int n_in,
                              void* d_out, int out_size, void* d_ws, size_t ws_size,
                              hipStream_t stream) {
    const int*   edge_index = (const int*)d_in[0];
    const float* norm       = (const float*)d_in[1];
    const int*   ctx_ids    = (const int*)d_in[2];
    const int*   miss_ids   = (const int*)d_in[3];
    const int*   vocab_to_fg= (const int*)d_in[4];
    const float* emb_table  = (const float*)d_in[5];
    const float* fg_emb     = (const float*)d_in[6];
    const float* gc_w       = (const float*)d_in[7];
    const float* bn_gamma   = (const float*)d_in[8];
    const float* bn_beta    = (const float*)d_in[9];
    const float* attn_w     = (const float*)d_in[10];
    const float* attn_b     = (const float*)d_in[11];
    const float* fusion_w   = (const float*)d_in[12];
    const float* fusion_b   = (const float*)d_in[13];
    const float* proj1_w    = (const float*)d_in[14];
    const float* proj1_b    = (const float*)d_in[15];
    const float* proj2_w    = (const float*)d_in[16];
    const float* proj2_b    = (const float*)d_in[17];

    const int* row = edge_index;
    const int* col = edge_index + NE;

    float* ws = (float*)d_ws;
    float*          z      = ws + OFF_Z;
    unsigned short* Ah     = (unsigned short*)(ws + OFF_AH);
    unsigned short* hbf    = (unsigned short*)(ws + OFF_HBF);
    float*          edge_s = ws + OFF_EDG;
    int*   row_start = (int*)(ws + OFF_RS);
    int*   cursor    = (int*)(ws + OFF_CUR);
    int*   counts    = (int*)(ws + OFF_CNT);
    float* stats     = ws + OFF_STAT;
    float* scsh      = ws + OFF_SCSH;
    unsigned short* Wh = (unsigned short*)(ws + OFF_WH);
    unsigned short* Wl = (unsigned short*)(ws + OFF_WL);
    int*   bsums     = (int*)(ws + OFF_BS);
    int*   boffs     = (int*)(ws + OFF_BO);

    float* query = (float*)d_out;
    float* G     = (float*)d_out + (size_t)NB * DIM;  // graph_embs, doubles as h

    hipMemsetAsync(counts, 0, NN * sizeof(int), stream);
    hipMemsetAsync(stats, 0, 256 * sizeof(float), stream);

    const int EB = (NE + 255) / 256;  // 3125
    wsplit_kernel<<<128, 256, 0, stream>>>(gc_w, Wh, Wl);
    cast_bf_kernel<<<6250, 256, 0, stream>>>(fg_emb, hbf);
    hist_kernel<<<EB, 256, 0, stream>>>(row, counts);
    scan_blocksums<<<SCAN_B, 256, 0, stream>>>(counts, bsums);
    scan_bsums<<<1, 256, 0, stream>>>(bsums, boffs);
    scan_final<<<SCAN_B, 256, 0, stream>>>(counts, boffs, row_start, cursor);
    scatter_kernel<<<EB, 256, 0, stream>>>(row, col, norm, cursor, edge_s);

    const int AGG_B = NN / 4;                 // 12500 blocks, one wave per row
    const int RES_B = (NN * DIM / 4) / 256;   // 6250
    dim3 gemm_grid(196, 4);                   // 784 blocks; y = 32-channel group

    // ---- layer 1 ----
    agg_bf_kernel<<<AGG_B, 256, 0, stream>>>(hbf, row_start, edge_s, Ah);
    gemm_mfma_kernel<<<gemm_grid, 256, 0, stream>>>(Ah, Wh, Wl, z, stats);
    bn_finalize_kernel<<<1, 128, 0, stream>>>(stats, bn_gamma, bn_beta, scsh);
    residual_kernel<<<RES_B, 256, 0, stream>>>(fg_emb, z, scsh, G, hbf);

    // ---- layer 2 ----
    agg_bf_kernel<<<AGG_B, 256, 0, stream>>>(hbf, row_start, edge_s, Ah);
    gemm_mfma_kernel<<<gemm_grid, 256, 0, stream>>>(Ah, Wh + DIM * DIM, Wl + DIM * DIM, z, stats);
    bn_finalize_kernel<<<1, 128, 0, stream>>>(stats, bn_gamma + 128, bn_beta + 128, scsh);
    residual_kernel<<<RES_B, 256, 0, stream>>>(G, z, scsh, G, nullptr);

    // ---- batch head ----
    batch_kernel<<<NB, 256, 0, stream>>>(ctx_ids, miss_ids, vocab_to_fg, emb_table, G,
                                         attn_w, attn_b, fusion_w, fusion_b,
                                         proj1_w, proj1_b, proj2_w, proj2_b, query);
}

// Round 7
// 323.021 us; speedup vs baseline: 2.8010x; 1.5162x over previous
//
#include <hip/hip_runtime.h>

#define NN 50000
#define NE 800000
#define DIM 128
#define NB 1024
#define CTXL 50
#define BN_EPS 1e-5f
#define STRIPS 3125   // NN/16
#define SCAN_B 196    // ceil(NN/256)
#define GEMM_BX 196   // gemm grid.x

// ---------------- ws layout (float offsets) ----------------
static const size_t OFF_Z    = 0;          // z fp32 [NN][128]          25.6 MB
static const size_t OFF_AH   = 6400000;    // Ah bf16 [NN][128]         12.8 MB
static const size_t OFF_HBF  = 9600000;    // hbf bf16 [NN][128]        12.8 MB (fgbf then Gbf)
static const size_t OFF_EDG  = 12800000;   // (col,norm) pairs [NE][2]   6.4 MB
static const size_t OFF_RS   = 14400000;   // row_start [NN+1] int
static const size_t OFF_CUR  = 14450048;   // cursor [NN] int; ALIASED by P2 after scatter
static const size_t OFF_CNT  = 14500096;   // counts [NN] int
static const size_t OFF_SCSH = 14550400;   // scale/shift [256] f
static const size_t OFF_WH   = 14550656;   // Wh bf16 [2][128][128]
static const size_t OFF_WL   = 14567040;   // Wl bf16 [2][128][128]
static const size_t OFF_BS   = 14583424;   // bsums [256] int
static const size_t OFF_BO   = 14583680;   // boffs [256] int
static const size_t OFF_P2   = OFF_CUR;    // BN partials [196][256] f (cursor is dead by gemm time)

typedef __attribute__((ext_vector_type(8))) short s16x8;
typedef __attribute__((ext_vector_type(4))) float fx4;

__device__ __forceinline__ unsigned short f2bf(float f) {
    unsigned u = __float_as_uint(f);
    unsigned r = u + 0x7FFFu + ((u >> 16) & 1u);
    return (unsigned short)(r >> 16);
}
__device__ __forceinline__ float bf2f(unsigned short b) {
    return __uint_as_float((unsigned)b << 16);
}

// ---------------- CSR build ----------------
__global__ void hist_kernel(const int* __restrict__ row, int* __restrict__ counts) {
    int e = blockIdx.x * 256 + threadIdx.x;
    if (e < NE) atomicAdd(&counts[row[e]], 1);
}

__global__ __launch_bounds__(256) void scan_blocksums(const int* __restrict__ counts,
                                                      int* __restrict__ bsums) {
    __shared__ int red[4];
    int i = blockIdx.x * 256 + threadIdx.x;
    int v = (i < NN) ? counts[i] : 0;
    #pragma unroll
    for (int off = 32; off; off >>= 1) v += __shfl_down(v, off);
    if ((threadIdx.x & 63) == 0) red[threadIdx.x >> 6] = v;
    __syncthreads();
    if (threadIdx.x == 0) bsums[blockIdx.x] = red[0] + red[1] + red[2] + red[3];
}

__global__ __launch_bounds__(256) void scan_bsums(const int* __restrict__ bsums,
                                                  int* __restrict__ boffs) {
    __shared__ int lds[256];
    int t = threadIdx.x;
    lds[t] = (t < SCAN_B) ? bsums[t] : 0;
    __syncthreads();
    for (int off = 1; off < 256; off <<= 1) {
        int add = (t >= off) ? lds[t - off] : 0;
        __syncthreads();
        lds[t] += add;
        __syncthreads();
    }
    boffs[t] = (t == 0) ? 0 : lds[t - 1];
}

__global__ __launch_bounds__(256) void scan_final(const int* __restrict__ counts,
                                                  const int* __restrict__ boffs,
                                                  int* __restrict__ row_start,
                                                  int* __restrict__ cursor) {
    __shared__ int lds[256];
    int t = threadIdx.x;
    int i = blockIdx.x * 256 + t;
    int v = (i < NN) ? counts[i] : 0;
    lds[t] = v;
    __syncthreads();
    for (int off = 1; off < 256; off <<= 1) {
        int add = (t >= off) ? lds[t - off] : 0;
        __syncthreads();
        lds[t] += add;
        __syncthreads();
    }
    int excl = boffs[blockIdx.x] + ((t == 0) ? 0 : lds[t - 1]);
    if (i < NN) {
        row_start[i] = excl;
        cursor[i] = excl;
    }
    if (i == 0) row_start[NN] = NE;
}

__global__ void scatter_kernel(const int* __restrict__ row, const int* __restrict__ col,
                               const float* __restrict__ norm, int* __restrict__ cursor,
                               float* __restrict__ edge_s) {
    int e = blockIdx.x * 256 + threadIdx.x;
    if (e < NE) {
        int r = row[e];
        int p = atomicAdd(&cursor[r], 1);
        ((int*)edge_s)[2 * p] = col[e];
        edge_s[2 * p + 1] = norm[e];
    }
}

// ---------------- prep: W split, h cast ----------------
__global__ void wsplit_kernel(const float* __restrict__ W, unsigned short* __restrict__ Wh,
                              unsigned short* __restrict__ Wl) {
    int i = blockIdx.x * 256 + threadIdx.x;
    if (i < 2 * DIM * DIM) {
        float v = W[i];
        unsigned short h = f2bf(v);
        Wh[i] = h;
        Wl[i] = f2bf(v - bf2f(h));
    }
}

__global__ void cast_bf_kernel(const float* __restrict__ in, unsigned short* __restrict__ out) {
    int i = blockIdx.x * 256 + threadIdx.x;  // float4 index
    if (i >= NN * DIM / 4) return;
    float4 v = reinterpret_cast<const float4*>(in)[i];
    ushort4 o = make_ushort4(f2bf(v.x), f2bf(v.y), f2bf(v.z), f2bf(v.w));
    reinterpret_cast<ushort4*>(out)[i] = o;
}

// ---------------- aggregation: one wave per row, gather bf16 rows, fp32 accum ----------------
__global__ __launch_bounds__(256) void agg_bf_kernel(const unsigned short* __restrict__ hbf,
                                                     const int* __restrict__ row_start,
                                                     const float* __restrict__ edge_s,
                                                     unsigned short* __restrict__ Ah) {
    int gw = (blockIdx.x * 256 + threadIdx.x) >> 6;
    int lane = threadIdx.x & 63;
    if (gw >= NN) return;
    int s = row_start[gw];
    int e = row_start[gw + 1];
    const int2* ep = (const int2*)edge_s;
    float ax = 0.f, ay = 0.f;
    int j = s;
    for (; j + 4 <= e; j += 4) {
        int2 p0 = ep[j], p1 = ep[j + 1], p2 = ep[j + 2], p3 = ep[j + 3];
        ushort2 v0 = *(const ushort2*)(hbf + (size_t)p0.x * DIM + lane * 2);
        ushort2 v1 = *(const ushort2*)(hbf + (size_t)p1.x * DIM + lane * 2);
        ushort2 v2 = *(const ushort2*)(hbf + (size_t)p2.x * DIM + lane * 2);
        ushort2 v3 = *(const ushort2*)(hbf + (size_t)p3.x * DIM + lane * 2);
        float w0 = __int_as_float(p0.y), w1 = __int_as_float(p1.y);
        float w2 = __int_as_float(p2.y), w3 = __int_as_float(p3.y);
        ax = fmaf(w0, bf2f(v0.x), ax); ay = fmaf(w0, bf2f(v0.y), ay);
        ax = fmaf(w1, bf2f(v1.x), ax); ay = fmaf(w1, bf2f(v1.y), ay);
        ax = fmaf(w2, bf2f(v2.x), ax); ay = fmaf(w2, bf2f(v2.y), ay);
        ax = fmaf(w3, bf2f(v3.x), ax); ay = fmaf(w3, bf2f(v3.y), ay);
    }
    for (; j < e; j++) {
        int2 p = ep[j];
        ushort2 v = *(const ushort2*)(hbf + (size_t)p.x * DIM + lane * 2);
        float w = __int_as_float(p.y);
        ax = fmaf(w, bf2f(v.x), ax); ay = fmaf(w, bf2f(v.y), ay);
    }
    *(ushort2*)(Ah + (size_t)gw * DIM + lane * 2) = make_ushort2(f2bf(ax), f2bf(ay));
}

// ---------------- z = relu(agg @ W^T) via MFMA, W staged in LDS, BN partials per block ----------------
// blockIdx.y = cq selects 32 channels. W (hi+lo planes, 32x128 each, 16 KB) staged to LDS
// (XOR chunk swizzle). A fragments read directly from global per lane.
// BN sums: per-wave shfl reduce -> LDS combine across 4 waves -> ONE coalesced 64-float
// partial row per block (NO global atomics -- the r6 profile showed ~100us of cross-XCD
// atomic drain on 16 hot cachelines).
__global__ __launch_bounds__(256) void gemm_mfma_kernel(const unsigned short* __restrict__ Ah,
                                                        const unsigned short* __restrict__ Wh,
                                                        const unsigned short* __restrict__ Wl,
                                                        float* __restrict__ z,
                                                        float* __restrict__ P2) {
    __shared__ __align__(16) short Wlds[2][32][128];  // 16 KB
    __shared__ float Pred[2][4][32];                  // [kind][wave][cpr]
    int tid = threadIdx.x;
    int lane = tid & 63;
    int w = tid >> 6;
    int r16 = lane & 15;
    int kg = lane >> 4;
    int cq = blockIdx.y;  // 0..3

    // stage W: 1024 16B-chunks, 4 per thread
    #pragma unroll
    for (int ff = 0; ff < 4; ff++) {
        int f = ff * 256 + tid;
        int plane = f >> 9;        // 0..1
        int c = (f >> 4) & 31;     // channel within cq group
        int ck = f & 15;           // 16B chunk within row
        const unsigned short* srcp = (plane ? Wl : Wh) + (size_t)(cq * 32 + c) * DIM + ck * 8;
        s16x8 v = *(const s16x8*)srcp;
        *(s16x8*)&Wlds[plane][c][(ck ^ (c & 7)) * 8] = v;
    }
    __syncthreads();

    int wv = (blockIdx.x * 256 + tid) >> 6;
    int nw = gridDim.x * 4;
    float bsum[2][4] = {{0.f}}, bsq[2][4] = {{0.f}};

    for (int strip = wv; strip < STRIPS; strip += nw) {
        size_t abase = (size_t)(strip * 16 + r16) * DIM + kg * 8;
        s16x8 b[4];
        #pragma unroll
        for (int ks = 0; ks < 4; ks++) b[ks] = *(const s16x8*)(Ah + abase + ks * 32);

        fx4 acc[2];
        acc[0] = (fx4){0.f, 0.f, 0.f, 0.f};
        acc[1] = (fx4){0.f, 0.f, 0.f, 0.f};
        #pragma unroll
        for (int ks = 0; ks < 4; ks++) {
            #pragma unroll
            for (int ct = 0; ct < 2; ct++) {
                int wrow = ct * 16 + r16;
                int wch = ((ks * 4 + kg) ^ (r16 & 7)) * 8;
                s16x8 wh8 = *(const s16x8*)&Wlds[0][wrow][wch];
                s16x8 wl8 = *(const s16x8*)&Wlds[1][wrow][wch];
                acc[ct] = __builtin_amdgcn_mfma_f32_16x16x32_bf16(wh8, b[ks], acc[ct], 0, 0, 0);
                acc[ct] = __builtin_amdgcn_mfma_f32_16x16x32_bf16(wl8, b[ks], acc[ct], 0, 0, 0);
            }
        }
        size_t zrow = (size_t)(strip * 16 + r16) * DIM + cq * 32 + kg * 4;
        #pragma unroll
        for (int ct = 0; ct < 2; ct++) {
            float4 o;
            o.x = fmaxf(acc[ct][0], 0.f);
            o.y = fmaxf(acc[ct][1], 0.f);
            o.z = fmaxf(acc[ct][2], 0.f);
            o.w = fmaxf(acc[ct][3], 0.f);
            bsum[ct][0] += o.x; bsq[ct][0] += o.x * o.x;
            bsum[ct][1] += o.y; bsq[ct][1] += o.y * o.y;
            bsum[ct][2] += o.z; bsq[ct][2] += o.z * o.z;
            bsum[ct][3] += o.w; bsq[ct][3] += o.w * o.w;
            *(float4*)(z + zrow + ct * 16) = o;
        }
    }

    // per-wave reduce over r16 (lane bits 0-3), then per-block combine in LDS
    #pragma unroll
    for (int ct = 0; ct < 2; ct++) {
        #pragma unroll
        for (int jj = 0; jj < 4; jj++) {
            float s = bsum[ct][jj], q = bsq[ct][jj];
            #pragma unroll
            for (int off = 1; off <= 8; off <<= 1) {
                s += __shfl_xor(s, off);
                q += __shfl_xor(q, off);
            }
            if (r16 == 0) {
                int cpr = ct * 16 + kg * 4 + jj;
                Pred[0][w][cpr] = s;
                Pred[1][w][cpr] = q;
            }
        }
    }
    __syncthreads();
    if (tid < 64) {  // tid = kind*32 + cpr
        int kind = tid >> 5, cpr = tid & 31;
        float v = (Pred[kind][0][cpr] + Pred[kind][1][cpr]) +
                  (Pred[kind][2][cpr] + Pred[kind][3][cpr]);
        P2[blockIdx.x * 256 + cq * 64 + tid] = v;
    }
}

// ---------------- BN finalize: reduce 196 partial rows + compute scale/shift ----------------
__global__ __launch_bounds__(256) void bn_finalize_kernel(const float* __restrict__ P2,
                                                          const float* __restrict__ gamma,
                                                          const float* __restrict__ beta,
                                                          float* __restrict__ scsh) {
    __shared__ float tot[256];
    int t = threadIdx.x;
    float a0 = 0.f, a1 = 0.f, a2 = 0.f, a3 = 0.f;
    for (int bx = 0; bx < GEMM_BX; bx += 4) {  // 196 = 4*49
        a0 += P2[(bx + 0) * 256 + t];
        a1 += P2[(bx + 1) * 256 + t];
        a2 += P2[(bx + 2) * 256 + t];
        a3 += P2[(bx + 3) * 256 + t];
    }
    tot[t] = (a0 + a1) + (a2 + a3);
    __syncthreads();
    if (t < 128) {  // channel c == t: cq = t>>5, cp = t&31
        int cq = t >> 5, cp = t & 31;
        float sum = tot[cq * 64 + cp];
        float sq  = tot[cq * 64 + 32 + cp];
        float mu = sum * (1.f / (float)NN);
        float var = sq * (1.f / (float)NN) - mu * mu;
        float sc = gamma[t] / sqrtf(var + BN_EPS);
        scsh[t] = sc;
        scsh[128 + t] = beta[t] - mu * sc;
    }
}

// ---------------- h_out = h_in + z*scale + shift (+ optional bf16 emit) ----------------
__global__ __launch_bounds__(256) void residual_kernel(const float* hin,
                                                       const float* z,
                                                       const float* __restrict__ scsh,
                                                       float* hout,
                                                       unsigned short* hbf_out) {
    int i = blockIdx.x * 256 + threadIdx.x;  // float4 index
    if (i >= NN * DIM / 4) return;
    int c = (i * 4) & 127;
    float4 zv = reinterpret_cast<const float4*>(z)[i];
    float4 hv = reinterpret_cast<const float4*>(hin)[i];
    float4 sc = *reinterpret_cast<const float4*>(scsh + c);
    float4 sh = *reinterpret_cast<const float4*>(scsh + 128 + c);
    float4 o;
    o.x = hv.x + zv.x * sc.x + sh.x;
    o.y = hv.y + zv.y * sc.y + sh.y;
    o.z = hv.z + zv.z * sc.z + sh.z;
    o.w = hv.w + zv.w * sc.w + sh.w;
    reinterpret_cast<float4*>(hout)[i] = o;
    if (hbf_out) {
        ushort4 ob = make_ushort4(f2bf(o.x), f2bf(o.y), f2bf(o.z), f2bf(o.w));
        reinterpret_cast<ushort4*>(hbf_out)[i] = ob;
    }
}

// ---------------- fused batch head ----------------
__global__ __launch_bounds__(256) void batch_kernel(const int* __restrict__ ctx_ids,
                                                    const int* __restrict__ miss_ids,
                                                    const int* __restrict__ vocab_to_fg,
                                                    const float* __restrict__ emb_table,
                                                    const float* __restrict__ graph,
                                                    const float* __restrict__ attn_w,
                                                    const float* __restrict__ attn_b,
                                                    const float* __restrict__ fusion_w,
                                                    const float* __restrict__ fusion_b,
                                                    const float* __restrict__ proj1_w,
                                                    const float* __restrict__ proj1_b,
                                                    const float* __restrict__ proj2_w,
                                                    const float* __restrict__ proj2_b,
                                                    float* __restrict__ query) {
    int b = blockIdx.x;
    int tid = threadIdx.x;
    __shared__ float ctx[CTXL][129];
    __shared__ float aw[128];
    __shared__ float lg[64];
    __shared__ __align__(16) float qin[256];
    __shared__ __align__(16) float cat[256];
    __shared__ __align__(16) float q1[256];

    if (tid < 128) aw[tid] = attn_w[tid];
    for (int f = tid; f < CTXL * 128; f += 256) {
        int t = f >> 7, d = f & 127;
        int vid = ctx_ids[b * CTXL + t];
        ctx[t][d] = emb_table[(size_t)vid * DIM + d];
    }
    __syncthreads();

    if (tid < CTXL) {
        float s = 0.f;
        for (int k = 0; k < 128; k++) s += ctx[tid][k] * aw[k];
        lg[tid] = s + attn_b[0];
    }
    __syncthreads();

    if (tid < 64) {
        float v = (tid < CTXL) ? lg[tid] : -INFINITY;
        float m = v;
        for (int off = 32; off; off >>= 1) m = fmaxf(m, __shfl_xor(m, off));
        float e = (tid < CTXL) ? expf(v - m) : 0.f;
        float s = e;
        for (int off = 32; off; off >>= 1) s += __shfl_xor(s, off);
        if (tid < CTXL) lg[tid] = e / s;
    }
    __syncthreads();

    if (tid < 128) {
        float s = 0.f;
        for (int t = 0; t < CTXL; t++) s += lg[t] * ctx[t][tid];
        qin[tid] = s;
    }
    int mid = miss_ids[b];
    if (tid < 128) {
        cat[tid] = emb_table[(size_t)mid * DIM + tid];
    } else {
        int d = tid - 128;
        int fg = vocab_to_fg[mid];
        cat[tid] = (fg >= 0) ? graph[(size_t)fg * DIM + d] : 0.f;
    }
    __syncthreads();

    if (tid < 128) {
        float s = fusion_b[tid];
        const float4* wr = reinterpret_cast<const float4*>(fusion_w + (size_t)tid * 256);
        const float4* cr = reinterpret_cast<const float4*>(cat);
        for (int k = 0; k < 64; k++) {
            float4 w4 = wr[k];
            float4 c4 = cr[k];
            s += w4.x * c4.x + w4.y * c4.y + w4.z * c4.z + w4.w * c4.w;
        }
        qin[128 + tid] = s;
    }
    __syncthreads();

    {
        float s = proj1_b[tid];
        const float4* wr = reinterpret_cast<const float4*>(proj1_w + (size_t)tid * 256);
        const float4* cr = reinterpret_cast<const float4*>(qin);
        for (int k = 0; k < 64; k++) {
            float4 w4 = wr[k];
            float4 c4 = cr[k];
            s += w4.x * c4.x + w4.y * c4.y + w4.z * c4.z + w4.w * c4.w;
        }
        q1[tid] = fmaxf(s, 0.f);
    }
    __syncthreads();

    if (tid < 128) {
        float s = proj2_b[tid];
        const float4* wr = reinterpret_cast<const float4*>(proj2_w + (size_t)tid * 256);
        const float4* cr = reinterpret_cast<const float4*>(q1);
        for (int k = 0; k < 64; k++) {
            float4 w4 = wr[k];
            float4 c4 = cr[k];
            s += w4.x * c4.x + w4.y * c4.y + w4.z * c4.z + w4.w * c4.w;
        }
        query[(size_t)b * DIM + tid] = s;
    }
}

extern "C" void kernel_launch(void* const* d_in, const int* in_sizes, int n_in,
                              void* d_out, int out_size, void* d_ws, size_t ws_size,
                              hipStream_t stream) {
    const int*   edge_index = (const int*)d_in[0];
    const float* norm       = (const float*)d_in[1];
    const int*   ctx_ids    = (const int*)d_in[2];
    const int*   miss_ids   = (const int*)d_in[3];
    const int*   vocab_to_fg= (const int*)d_in[4];
    const float* emb_table  = (const float*)d_in[5];
    const float* fg_emb     = (const float*)d_in[6];
    const float* gc_w       = (const float*)d_in[7];
    const float* bn_gamma   = (const float*)d_in[8];
    const float* bn_beta   = (const float*)d_in[9];
    const float* attn_w     = (const float*)d_in[10];
    const float* attn_b     = (const float*)d_in[11];
    const float* fusion_w   = (const float*)d_in[12];
    const float* fusion_b   = (const float*)d_in[13];
    const float* proj1_w    = (const float*)d_in[14];
    const float* proj1_b    = (const float*)d_in[15];
    const float* proj2_w    = (const float*)d_in[16];
    const float* proj2_b    = (const float*)d_in[17];

    const int* row = edge_index;
    const int* col = edge_index + NE;

    float* ws = (float*)d_ws;
    float*          z      = ws + OFF_Z;
    unsigned short* Ah     = (unsigned short*)(ws + OFF_AH);
    unsigned short* hbf    = (unsigned short*)(ws + OFF_HBF);
    float*          edge_s = ws + OFF_EDG;
    int*   row_start = (int*)(ws + OFF_RS);
    int*   cursor    = (int*)(ws + OFF_CUR);
    int*   counts    = (int*)(ws + OFF_CNT);
    float* scsh      = ws + OFF_SCSH;
    unsigned short* Wh = (unsigned short*)(ws + OFF_WH);
    unsigned short* Wl = (unsigned short*)(ws + OFF_WL);
    int*   bsums     = (int*)(ws + OFF_BS);
    int*   boffs     = (int*)(ws + OFF_BO);
    float* P2        = ws + OFF_P2;  // aliases cursor (dead after scatter)

    float* query = (float*)d_out;
    float* G     = (float*)d_out + (size_t)NB * DIM;  // graph_embs, doubles as h

    hipMemsetAsync(counts, 0, NN * sizeof(int), stream);

    const int EB = (NE + 255) / 256;  // 3125
    wsplit_kernel<<<128, 256, 0, stream>>>(gc_w, Wh, Wl);
    cast_bf_kernel<<<6250, 256, 0, stream>>>(fg_emb, hbf);
    hist_kernel<<<EB, 256, 0, stream>>>(row, counts);
    scan_blocksums<<<SCAN_B, 256, 0, stream>>>(counts, bsums);
    scan_bsums<<<1, 256, 0, stream>>>(bsums, boffs);
    scan_final<<<SCAN_B, 256, 0, stream>>>(counts, boffs, row_start, cursor);
    scatter_kernel<<<EB, 256, 0, stream>>>(row, col, norm, cursor, edge_s);

    const int AGG_B = NN / 4;                 // 12500 blocks, one wave per row
    const int RES_B = (NN * DIM / 4) / 256;   // 6250
    dim3 gemm_grid(GEMM_BX, 4);               // 784 blocks; y = 32-channel group

    // ---- layer 1 ----
    agg_bf_kernel<<<AGG_B, 256, 0, stream>>>(hbf, row_start, edge_s, Ah);
    gemm_mfma_kernel<<<gemm_grid, 256, 0, stream>>>(Ah, Wh, Wl, z, P2);
    bn_finalize_kernel<<<1, 256, 0, stream>>>(P2, bn_gamma, bn_beta, scsh);
    residual_kernel<<<RES_B, 256, 0, stream>>>(fg_emb, z, scsh, G, hbf);

    // ---- layer 2 ----
    agg_bf_kernel<<<AGG_B, 256, 0, stream>>>(hbf, row_start, edge_s, Ah);
    gemm_mfma_kernel<<<gemm_grid, 256, 0, stream>>>(Ah, Wh + DIM * DIM, Wl + DIM * DIM, z, P2);
    bn_finalize_kernel<<<1, 256, 0, stream>>>(P2, bn_gamma + 128, bn_beta + 128, scsh);
    residual_kernel<<<RES_B, 256, 0, stream>>>(G, z, scsh, G, nullptr);

    // ---- batch head ----
    batch_kernel<<<NB, 256, 0, stream>>>(ctx_ids, miss_ids, vocab_to_fg, emb_table, G,
                                         attn_w, attn_b, fusion_w, fusion_b,
                                         proj1_w, proj1_b, proj2_w, proj2_b, query);
}

// Round 9
// 274.545 us; speedup vs baseline: 3.2956x; 1.1766x over previous
//
#include <hip/hip_runtime.h>

#define NN 50000
#define NE 800000
#define DIM 128
#define NB 1024
#define CTXL 50
#define BN_EPS 1e-5f
#define STRIPS 3125   // NN/16
#define SCAN_B 196    // ceil(NN/256)
#define GEMM_BX 196   // gemm grid.x

// ---------------- ws layout (float offsets) ----------------
static const size_t OFF_Z    = 0;          // z fp32 [NN][128] 25.6 MB; head aliases below (z dead)
static const size_t OFF_AH   = 6400000;    // Ah bf16 [NN][128]         12.8 MB
static const size_t OFF_HBF  = 9600000;    // hbf bf16 [NN][128]        12.8 MB (fgbf then Gbf)
static const size_t OFF_EDG  = 12800000;   // (col,norm) pairs [NE][2]   6.4 MB
static const size_t OFF_RS   = 14400000;   // row_start [NN+1] int
static const size_t OFF_CUR  = 14450048;   // cursor [NN] int; ALIASED by P2 after scatter
static const size_t OFF_CNT  = 14500096;   // counts [NN] int
static const size_t OFF_SCSH = 14550400;   // scale/shift [256] f
static const size_t OFF_WH   = 14550656;   // Wh bf16 [2][128][128]
static const size_t OFF_WL   = 14567040;   // Wl bf16 [2][128][128]
static const size_t OFF_BS   = 14583424;   // bsums [256] int
static const size_t OFF_BO   = 14583680;   // boffs [256] int   (end 14583936 == r7 extent)
static const size_t OFF_P2   = OFF_CUR;    // BN partials [196][256] f
// head aliases inside dead z region: each bf16 [1024][256] = 131072 floats
static const size_t OFF_QIN  = OFF_Z;            // qin bf16
static const size_t OFF_CAT  = OFF_Z + 131072;   // cat bf16
static const size_t OFF_Q1   = OFF_Z + 262144;   // q1  bf16
static const size_t OFF_FWB  = OFF_Z + 393216;   // fusion_w bf16 [128][256] -> 16384 f
static const size_t OFF_P1B  = OFF_Z + 409600;   // proj1_w  bf16 [256][256] -> 32768 f
static const size_t OFF_P2B  = OFF_Z + 442368;   // proj2_w  bf16 [128][256] -> 16384 f (end 458752)

typedef __attribute__((ext_vector_type(8))) short s16x8;
typedef __attribute__((ext_vector_type(4))) float fx4;

__device__ __forceinline__ unsigned short f2bf(float f) {
    unsigned u = __float_as_uint(f);
    unsigned r = u + 0x7FFFu + ((u >> 16) & 1u);
    return (unsigned short)(r >> 16);
}
__device__ __forceinline__ float bf2f(unsigned short b) {
    return __uint_as_float((unsigned)b << 16);
}

// ---------------- CSR build ----------------
__global__ void hist_kernel(const int* __restrict__ row, int* __restrict__ counts) {
    int e = blockIdx.x * 256 + threadIdx.x;
    if (e < NE) atomicAdd(&counts[row[e]], 1);
}

__global__ __launch_bounds__(256) void scan_blocksums(const int* __restrict__ counts,
                                                      int* __restrict__ bsums) {
    __shared__ int red[4];
    int i = blockIdx.x * 256 + threadIdx.x;
    int v = (i < NN) ? counts[i] : 0;
    #pragma unroll
    for (int off = 32; off; off >>= 1) v += __shfl_down(v, off);
    if ((threadIdx.x & 63) == 0) red[threadIdx.x >> 6] = v;
    __syncthreads();
    if (threadIdx.x == 0) bsums[blockIdx.x] = red[0] + red[1] + red[2] + red[3];
}

__global__ __launch_bounds__(256) void scan_bsums(const int* __restrict__ bsums,
                                                  int* __restrict__ boffs) {
    __shared__ int lds[256];
    int t = threadIdx.x;
    lds[t] = (t < SCAN_B) ? bsums[t] : 0;
    __syncthreads();
    for (int off = 1; off < 256; off <<= 1) {
        int add = (t >= off) ? lds[t - off] : 0;
        __syncthreads();
        lds[t] += add;
        __syncthreads();
    }
    boffs[t] = (t == 0) ? 0 : lds[t - 1];
}

__global__ __launch_bounds__(256) void scan_final(const int* __restrict__ counts,
                                                  const int* __restrict__ boffs,
                                                  int* __restrict__ row_start,
                                                  int* __restrict__ cursor) {
    __shared__ int lds[256];
    int t = threadIdx.x;
    int i = blockIdx.x * 256 + t;
    int v = (i < NN) ? counts[i] : 0;
    lds[t] = v;
    __syncthreads();
    for (int off = 1; off < 256; off <<= 1) {
        int add = (t >= off) ? lds[t - off] : 0;
        __syncthreads();
        lds[t] += add;
        __syncthreads();
    }
    int excl = boffs[blockIdx.x] + ((t == 0) ? 0 : lds[t - 1]);
    if (i < NN) {
        row_start[i] = excl;
        cursor[i] = excl;
    }
    if (i == 0) row_start[NN] = NE;
}

__global__ void scatter_kernel(const int* __restrict__ row, const int* __restrict__ col,
                               const float* __restrict__ norm, int* __restrict__ cursor,
                               float* __restrict__ edge_s) {
    int e = blockIdx.x * 256 + threadIdx.x;
    if (e < NE) {
        int r = row[e];
        int p = atomicAdd(&cursor[r], 1);
        ((int*)edge_s)[2 * p] = col[e];
        edge_s[2 * p + 1] = norm[e];
    }
}

// ---------------- prep: W split, h cast, head-weight cast ----------------
__global__ void wsplit_kernel(const float* __restrict__ W, unsigned short* __restrict__ Wh,
                              unsigned short* __restrict__ Wl) {
    int i = blockIdx.x * 256 + threadIdx.x;
    if (i < 2 * DIM * DIM) {
        float v = W[i];
        unsigned short h = f2bf(v);
        Wh[i] = h;
        Wl[i] = f2bf(v - bf2f(h));
    }
}

__global__ void cast_bf_kernel(const float* __restrict__ in, unsigned short* __restrict__ out) {
    int i = blockIdx.x * 256 + threadIdx.x;  // float4 index
    if (i >= NN * DIM / 4) return;
    float4 v = reinterpret_cast<const float4*>(in)[i];
    ushort4 o = make_ushort4(f2bf(v.x), f2bf(v.y), f2bf(v.z), f2bf(v.w));
    reinterpret_cast<ushort4*>(out)[i] = o;
}

__global__ void headw_cast_kernel(const float* __restrict__ fw, const float* __restrict__ p1,
                                  const float* __restrict__ p2, unsigned short* __restrict__ fwb,
                                  unsigned short* __restrict__ p1b, unsigned short* __restrict__ p2b) {
    int i = blockIdx.x * 256 + threadIdx.x;
    if (i < 32768) fwb[i] = f2bf(fw[i]);
    if (i < 65536) p1b[i] = f2bf(p1[i]);
    if (i < 32768) p2b[i] = f2bf(p2[i]);
}

// ---------------- aggregation: one wave per row, gather bf16 rows, fp32 accum ----------------
__global__ __launch_bounds__(256) void agg_bf_kernel(const unsigned short* __restrict__ hbf,
                                                     const int* __restrict__ row_start,
                                                     const float* __restrict__ edge_s,
                                                     unsigned short* __restrict__ Ah) {
    int gw = (blockIdx.x * 256 + threadIdx.x) >> 6;
    int lane = threadIdx.x & 63;
    if (gw >= NN) return;
    int s = row_start[gw];
    int e = row_start[gw + 1];
    const int2* ep = (const int2*)edge_s;
    float ax = 0.f, ay = 0.f;
    int j = s;
    for (; j + 4 <= e; j += 4) {
        int2 p0 = ep[j], p1 = ep[j + 1], p2 = ep[j + 2], p3 = ep[j + 3];
        ushort2 v0 = *(const ushort2*)(hbf + (size_t)p0.x * DIM + lane * 2);
        ushort2 v1 = *(const ushort2*)(hbf + (size_t)p1.x * DIM + lane * 2);
        ushort2 v2 = *(const ushort2*)(hbf + (size_t)p2.x * DIM + lane * 2);
        ushort2 v3 = *(const ushort2*)(hbf + (size_t)p3.x * DIM + lane * 2);
        float w0 = __int_as_float(p0.y), w1 = __int_as_float(p1.y);
        float w2 = __int_as_float(p2.y), w3 = __int_as_float(p3.y);
        ax = fmaf(w0, bf2f(v0.x), ax); ay = fmaf(w0, bf2f(v0.y), ay);
        ax = fmaf(w1, bf2f(v1.x), ax); ay = fmaf(w1, bf2f(v1.y), ay);
        ax = fmaf(w2, bf2f(v2.x), ax); ay = fmaf(w2, bf2f(v2.y), ay);
        ax = fmaf(w3, bf2f(v3.x), ax); ay = fmaf(w3, bf2f(v3.y), ay);
    }
    for (; j < e; j++) {
        int2 p = ep[j];
        ushort2 v = *(const ushort2*)(hbf + (size_t)p.x * DIM + lane * 2);
        float w = __int_as_float(p.y);
        ax = fmaf(w, bf2f(v.x), ax); ay = fmaf(w, bf2f(v.y), ay);
    }
    *(ushort2*)(Ah + (size_t)gw * DIM + lane * 2) = make_ushort2(f2bf(ax), f2bf(ay));
}

// ---------------- z = relu(agg @ W^T) via MFMA, W staged in LDS, BN partials per block ----------------
__global__ __launch_bounds__(256) void gemm_mfma_kernel(const unsigned short* __restrict__ Ah,
                                                        const unsigned short* __restrict__ Wh,
                                                        const unsigned short* __restrict__ Wl,
                                                        float* __restrict__ z,
                                                        float* __restrict__ P2) {
    __shared__ __align__(16) short Wlds[2][32][128];  // 16 KB
    __shared__ float Pred[2][4][32];                  // [kind][wave][cpr]
    int tid = threadIdx.x;
    int lane = tid & 63;
    int w = tid >> 6;
    int r16 = lane & 15;
    int kg = lane >> 4;
    int cq = blockIdx.y;  // 0..3

    #pragma unroll
    for (int ff = 0; ff < 4; ff++) {
        int f = ff * 256 + tid;
        int plane = f >> 9;
        int c = (f >> 4) & 31;
        int ck = f & 15;
        const unsigned short* srcp = (plane ? Wl : Wh) + (size_t)(cq * 32 + c) * DIM + ck * 8;
        s16x8 v = *(const s16x8*)srcp;
        *(s16x8*)&Wlds[plane][c][(ck ^ (c & 7)) * 8] = v;
    }
    __syncthreads();

    int wv = (blockIdx.x * 256 + tid) >> 6;
    int nw = gridDim.x * 4;
    float bsum[2][4] = {{0.f}}, bsq[2][4] = {{0.f}};

    for (int strip = wv; strip < STRIPS; strip += nw) {
        size_t abase = (size_t)(strip * 16 + r16) * DIM + kg * 8;
        s16x8 b[4];
        #pragma unroll
        for (int ks = 0; ks < 4; ks++) b[ks] = *(const s16x8*)(Ah + abase + ks * 32);

        fx4 acc[2];
        acc[0] = (fx4){0.f, 0.f, 0.f, 0.f};
        acc[1] = (fx4){0.f, 0.f, 0.f, 0.f};
        #pragma unroll
        for (int ks = 0; ks < 4; ks++) {
            #pragma unroll
            for (int ct = 0; ct < 2; ct++) {
                int wrow = ct * 16 + r16;
                int wch = ((ks * 4 + kg) ^ (r16 & 7)) * 8;
                s16x8 wh8 = *(const s16x8*)&Wlds[0][wrow][wch];
                s16x8 wl8 = *(const s16x8*)&Wlds[1][wrow][wch];
                acc[ct] = __builtin_amdgcn_mfma_f32_16x16x32_bf16(wh8, b[ks], acc[ct], 0, 0, 0);
                acc[ct] = __builtin_amdgcn_mfma_f32_16x16x32_bf16(wl8, b[ks], acc[ct], 0, 0, 0);
            }
        }
        size_t zrow = (size_t)(strip * 16 + r16) * DIM + cq * 32 + kg * 4;
        #pragma unroll
        for (int ct = 0; ct < 2; ct++) {
            float4 o;
            o.x = fmaxf(acc[ct][0], 0.f);
            o.y = fmaxf(acc[ct][1], 0.f);
            o.z = fmaxf(acc[ct][2], 0.f);
            o.w = fmaxf(acc[ct][3], 0.f);
            bsum[ct][0] += o.x; bsq[ct][0] += o.x * o.x;
            bsum[ct][1] += o.y; bsq[ct][1] += o.y * o.y;
            bsum[ct][2] += o.z; bsq[ct][2] += o.z * o.z;
            bsum[ct][3] += o.w; bsq[ct][3] += o.w * o.w;
            *(float4*)(z + zrow + ct * 16) = o;
        }
    }

    #pragma unroll
    for (int ct = 0; ct < 2; ct++) {
        #pragma unroll
        for (int jj = 0; jj < 4; jj++) {
            float s = bsum[ct][jj], q = bsq[ct][jj];
            #pragma unroll
            for (int off = 1; off <= 8; off <<= 1) {
                s += __shfl_xor(s, off);
                q += __shfl_xor(q, off);
            }
            if (r16 == 0) {
                int cpr = ct * 16 + kg * 4 + jj;
                Pred[0][w][cpr] = s;
                Pred[1][w][cpr] = q;
            }
        }
    }
    __syncthreads();
    if (tid < 64) {
        int kind = tid >> 5, cpr = tid & 31;
        float v = (Pred[kind][0][cpr] + Pred[kind][1][cpr]) +
                  (Pred[kind][2][cpr] + Pred[kind][3][cpr]);
        P2[blockIdx.x * 256 + cq * 64 + tid] = v;
    }
}

// ---------------- BN finalize ----------------
__global__ __launch_bounds__(256) void bn_finalize_kernel(const float* __restrict__ P2,
                                                          const float* __restrict__ gamma,
                                                          const float* __restrict__ beta,
                                                          float* __restrict__ scsh) {
    __shared__ float tot[256];
    int t = threadIdx.x;
    float a0 = 0.f, a1 = 0.f, a2 = 0.f, a3 = 0.f;
    for (int bx = 0; bx < GEMM_BX; bx += 4) {
        a0 += P2[(bx + 0) * 256 + t];
        a1 += P2[(bx + 1) * 256 + t];
        a2 += P2[(bx + 2) * 256 + t];
        a3 += P2[(bx + 3) * 256 + t];
    }
    tot[t] = (a0 + a1) + (a2 + a3);
    __syncthreads();
    if (t < 128) {
        int cq = t >> 5, cp = t & 31;
        float sum = tot[cq * 64 + cp];
        float sq  = tot[cq * 64 + 32 + cp];
        float mu = sum * (1.f / (float)NN);
        float var = sq * (1.f / (float)NN) - mu * mu;
        float sc = gamma[t] / sqrtf(var + BN_EPS);
        scsh[t] = sc;
        scsh[128 + t] = beta[t] - mu * sc;
    }
}

// ---------------- h_out = h_in + z*scale + shift (+ optional bf16 emit) ----------------
__global__ __launch_bounds__(256) void residual_kernel(const float* hin,
                                                       const float* z,
                                                       const float* __restrict__ scsh,
                                                       float* hout,
                                                       unsigned short* hbf_out) {
    int i = blockIdx.x * 256 + threadIdx.x;
    if (i >= NN * DIM / 4) return;
    int c = (i * 4) & 127;
    float4 zv = reinterpret_cast<const float4*>(z)[i];
    float4 hv = reinterpret_cast<const float4*>(hin)[i];
    float4 sc = *reinterpret_cast<const float4*>(scsh + c);
    float4 sh = *reinterpret_cast<const float4*>(scsh + 128 + c);
    float4 o;
    o.x = hv.x + zv.x * sc.x + sh.x;
    o.y = hv.y + zv.y * sc.y + sh.y;
    o.z = hv.z + zv.z * sc.z + sh.z;
    o.w = hv.w + zv.w * sc.w + sh.w;
    reinterpret_cast<float4*>(hout)[i] = o;
    if (hbf_out) {
        ushort4 ob = make_ushort4(f2bf(o.x), f2bf(o.y), f2bf(o.z), f2bf(o.w));
        reinterpret_cast<ushort4*>(hbf_out)[i] = ob;
    }
}

// ---------------- pool: attention pooling + cat build (bf16 rows out) ----------------
__global__ __launch_bounds__(256) void pool_kernel(const int* __restrict__ ctx_ids,
                                                   const int* __restrict__ miss_ids,
                                                   const int* __restrict__ vocab_to_fg,
                                                   const float* __restrict__ emb_table,
                                                   const float* __restrict__ graph,
                                                   const float* __restrict__ attn_w,
                                                   const float* __restrict__ attn_b,
                                                   unsigned short* __restrict__ qinb,
                                                   unsigned short* __restrict__ catb) {
    int b = blockIdx.x;
    int tid = threadIdx.x;
    __shared__ float ctx[CTXL][129];
    __shared__ float aw[128];
    __shared__ float lg[64];

    if (tid < 128) aw[tid] = attn_w[tid];
    for (int f = tid; f < CTXL * 128; f += 256) {
        int t = f >> 7, d = f & 127;
        int vid = ctx_ids[b * CTXL + t];
        ctx[t][d] = emb_table[(size_t)vid * DIM + d];
    }
    __syncthreads();

    if (tid < CTXL) {
        float s = 0.f;
        for (int k = 0; k < 128; k++) s += ctx[tid][k] * aw[k];
        lg[tid] = s + attn_b[0];
    }
    __syncthreads();

    if (tid < 64) {
        float v = (tid < CTXL) ? lg[tid] : -INFINITY;
        float m = v;
        for (int off = 32; off; off >>= 1) m = fmaxf(m, __shfl_xor(m, off));
        float e = (tid < CTXL) ? expf(v - m) : 0.f;
        float s = e;
        for (int off = 32; off; off >>= 1) s += __shfl_xor(s, off);
        if (tid < CTXL) lg[tid] = e / s;
    }
    __syncthreads();

    int mid = miss_ids[b];
    if (tid < 128) {
        float s = 0.f;
        for (int t = 0; t < CTXL; t++) s += lg[t] * ctx[t][tid];
        qinb[(size_t)b * 256 + tid] = f2bf(s);
        catb[(size_t)b * 256 + tid] = f2bf(emb_table[(size_t)mid * DIM + tid]);
    } else {
        int d = tid - 128;
        int fg = vocab_to_fg[mid];
        float gp = (fg >= 0) ? graph[(size_t)fg * DIM + d] : 0.f;
        catb[(size_t)b * 256 + tid] = f2bf(gp);
    }
}

// ---------------- head GEMM: out[r][cgb+c] = A[r][:]@W[cgb+c][:] + bias, optional relu ----------------
__global__ __launch_bounds__(256) void head_gemm_kernel(const unsigned short* __restrict__ A,
                                                        const unsigned short* __restrict__ W,
                                                        const float* __restrict__ bias,
                                                        unsigned short* __restrict__ outb,
                                                        float* __restrict__ outf,
                                                        int ocol, int ostride, int relu) {
    __shared__ __align__(16) short Wlds[64][256];  // 32 KB
    int tid = threadIdx.x;
    int lane = tid & 63;
    int r16 = lane & 15;
    int kg = lane >> 4;
    int cgb = blockIdx.y * 64;

    #pragma unroll
    for (int ff = 0; ff < 8; ff++) {
        int f = ff * 256 + tid;
        int c = f >> 5;
        int ck = f & 31;
        s16x8 v = *(const s16x8*)(W + (size_t)(cgb + c) * 256 + ck * 8);
        *(s16x8*)&Wlds[c][(ck ^ (c & 7)) * 8] = v;
    }
    __syncthreads();

    int w = tid >> 6;
    int row = blockIdx.x * 16 + r16;

    size_t abase = (size_t)row * 256 + kg * 8;
    s16x8 bfrag[8];
    #pragma unroll
    for (int ks = 0; ks < 8; ks++) bfrag[ks] = *(const s16x8*)(A + abase + ks * 32);

    fx4 acc = (fx4){0.f, 0.f, 0.f, 0.f};
    int wrow = w * 16 + r16;
    #pragma unroll
    for (int ks = 0; ks < 8; ks++) {
        int wch = (((ks * 4 + kg) ^ (r16 & 7))) * 8;
        s16x8 w8 = *(const s16x8*)&Wlds[wrow][wch];
        acc = __builtin_amdgcn_mfma_f32_16x16x32_bf16(w8, bfrag[ks], acc, 0, 0, 0);
    }

    int cbase = cgb + w * 16 + kg * 4;
    float4 o;
    o.x = acc[0] + bias[cbase + 0];
    o.y = acc[1] + bias[cbase + 1];
    o.z = acc[2] + bias[cbase + 2];
    o.w = acc[3] + bias[cbase + 3];
    if (relu) {
        o.x = fmaxf(o.x, 0.f); o.y = fmaxf(o.y, 0.f);
        o.z = fmaxf(o.z, 0.f); o.w = fmaxf(o.w, 0.f);
    }
    size_t op = (size_t)row * ostride + ocol + cbase;   // FIX: include cgb (via cbase)
    if (outb) {
        *(ushort4*)(outb + op) = make_ushort4(f2bf(o.x), f2bf(o.y), f2bf(o.z), f2bf(o.w));
    } else {
        *(float4*)(outf + op) = o;
    }
}

extern "C" void kernel_launch(void* const* d_in, const int* in_sizes, int n_in,
                              void* d_out, int out_size, void* d_ws, size_t ws_size,
                              hipStream_t stream) {
    const int*   edge_index = (const int*)d_in[0];
    const float* norm       = (const float*)d_in[1];
    const int*   ctx_ids    = (const int*)d_in[2];
    const int*   miss_ids   = (const int*)d_in[3];
    const int*   vocab_to_fg= (const int*)d_in[4];
    const float* emb_table  = (const float*)d_in[5];
    const float* fg_emb     = (const float*)d_in[6];
    const float* gc_w       = (const float*)d_in[7];
    const float* bn_gamma   = (const float*)d_in[8];
    const float* bn_beta    = (const float*)d_in[9];
    const float* attn_w     = (const float*)d_in[10];
    const float* attn_b     = (const float*)d_in[11];
    const float* fusion_w   = (const float*)d_in[12];
    const float* fusion_b   = (const float*)d_in[13];
    const float* proj1_w    = (const float*)d_in[14];
    const float* proj1_b    = (const float*)d_in[15];
    const float* proj2_w    = (const float*)d_in[16];
    const float* proj2_b    = (const float*)d_in[17];

    const int* row = edge_index;
    const int* col = edge_index + NE;

    float* ws = (float*)d_ws;
    float*          z      = ws + OFF_Z;
    unsigned short* Ah     = (unsigned short*)(ws + OFF_AH);
    unsigned short* hbf    = (unsigned short*)(ws + OFF_HBF);
    float*          edge_s = ws + OFF_EDG;
    int*   row_start = (int*)(ws + OFF_RS);
    int*   cursor    = (int*)(ws + OFF_CUR);
    int*   counts    = (int*)(ws + OFF_CNT);
    float* scsh      = ws + OFF_SCSH;
    unsigned short* Wh = (unsigned short*)(ws + OFF_WH);
    unsigned short* Wl = (unsigned short*)(ws + OFF_WL);
    int*   bsums     = (int*)(ws + OFF_BS);
    int*   boffs     = (int*)(ws + OFF_BO);
    float* P2        = ws + OFF_P2;
    unsigned short* qinb = (unsigned short*)(ws + OFF_QIN);
    unsigned short* catb = (unsigned short*)(ws + OFF_CAT);
    unsigned short* q1b  = (unsigned short*)(ws + OFF_Q1);
    unsigned short* fwb  = (unsigned short*)(ws + OFF_FWB);
    unsigned short* p1b  = (unsigned short*)(ws + OFF_P1B);
    unsigned short* p2b  = (unsigned short*)(ws + OFF_P2B);

    float* query = (float*)d_out;
    float* G     = (float*)d_out + (size_t)NB * DIM;  // graph_embs, doubles as h

    hipMemsetAsync(counts, 0, NN * sizeof(int), stream);

    const int EB = (NE + 255) / 256;  // 3125
    wsplit_kernel<<<128, 256, 0, stream>>>(gc_w, Wh, Wl);
    cast_bf_kernel<<<6250, 256, 0, stream>>>(fg_emb, hbf);
    hist_kernel<<<EB, 256, 0, stream>>>(row, counts);
    scan_blocksums<<<SCAN_B, 256, 0, stream>>>(counts, bsums);
    scan_bsums<<<1, 256, 0, stream>>>(bsums, boffs);
    scan_final<<<SCAN_B, 256, 0, stream>>>(counts, boffs, row_start, cursor);
    scatter_kernel<<<EB, 256, 0, stream>>>(row, col, norm, cursor, edge_s);

    const int AGG_B = NN / 4;                 // 12500 blocks, one wave per row
    const int RES_B = (NN * DIM / 4) / 256;   // 6250
    dim3 gemm_grid(GEMM_BX, 4);

    // ---- layer 1 ----
    agg_bf_kernel<<<AGG_B, 256, 0, stream>>>(hbf, row_start, edge_s, Ah);
    gemm_mfma_kernel<<<gemm_grid, 256, 0, stream>>>(Ah, Wh, Wl, z, P2);
    bn_finalize_kernel<<<1, 256, 0, stream>>>(P2, bn_gamma, bn_beta, scsh);
    residual_kernel<<<RES_B, 256, 0, stream>>>(fg_emb, z, scsh, G, hbf);

    // ---- layer 2 ----
    agg_bf_kernel<<<AGG_B, 256, 0, stream>>>(hbf, row_start, edge_s, Ah);
    gemm_mfma_kernel<<<gemm_grid, 256, 0, stream>>>(Ah, Wh + DIM * DIM, Wl + DIM * DIM, z, P2);
    bn_finalize_kernel<<<1, 256, 0, stream>>>(P2, bn_gamma + 128, bn_beta + 128, scsh);
    residual_kernel<<<RES_B, 256, 0, stream>>>(G, z, scsh, G, nullptr);

    // ---- batch head: z region now dead -> head aliases live there ----
    headw_cast_kernel<<<256, 256, 0, stream>>>(fusion_w, proj1_w, proj2_w, fwb, p1b, p2b);
    pool_kernel<<<NB, 256, 0, stream>>>(ctx_ids, miss_ids, vocab_to_fg, emb_table, G,
                                        attn_w, attn_b, qinb, catb);
    dim3 hg2(64, 2), hg4(64, 4);
    // miss_emb = cat @ fusion^T -> qin[:,128:256]
    head_gemm_kernel<<<hg2, 256, 0, stream>>>(catb, fwb, fusion_b, qinb, nullptr, 128, 256, 0);
    // q1 = relu(qin @ proj1^T)
    head_gemm_kernel<<<hg4, 256, 0, stream>>>(qinb, p1b, proj1_b, q1b, nullptr, 0, 256, 1);
    // query = q1 @ proj2^T
    head_gemm_kernel<<<hg2, 256, 0, stream>>>(q1b, p2b, proj2_b, nullptr, query, 0, 128, 0);
}